// Round 10
// baseline (332.976 us; speedup 1.0000x reference)
//
#include <hip/hip_runtime.h>
#include <hip/hip_bf16.h>

// Problem: B=4, S=2048, H=1024, NH=16, DK=64. fp32 I/O.
// R18: attn = R17 minus the Vs LDS round-trip. Pipe ledger (R17 counters):
// LDS pipe ~85us of the 102us attn (61 base + 24 conflict), VALU 27, MFMA 7.
// V's LDS traffic (2 staging b128 writes + 8 frag b128 reads per wave-kt =
// half the b128 ops) moves to the VMEM pipe: V-fragments are loaded DIRECT
// from global into registers. With the XCD swizzle K/V is L2-resident
// (FETCH 24.6MB proves it), and the pattern is perfectly coalesced: lane
// (col,quad) reads 16B at Vtg[(ds*16+col)*S + kt*64 + {0,32}+quad*8] ->
// 16 x 64B cachelines per instruction. Operand values bit-identical (same
// bf16 from the same buffer) -> zero numeric change. LDS: 27.6KB (Ks+Ps).
// Loads issued right after the staging barrier; QK^T+exp (~400cy) + 16
// waves/CU hide L2 latency. Everything else identical to R17.

typedef __hip_bfloat16 bf16;
typedef __attribute__((ext_vector_type(8))) short bf16x8;  // 8 bf16 = 4 VGPRs
typedef __attribute__((ext_vector_type(4))) float f32x4;

#define B_   4
#define S_   2048
#define H_   1024
#define NH_  16
#define DK_  64
#define M_   8192   // B_*S_
#define N1_  3072
#define K_   1024

#define SCALE_Q 0.18033688f   // 0.125 * log2(e): softmax in exp2 domain

typedef const __attribute__((address_space(1))) void* gas_t;
typedef __attribute__((address_space(3))) void* las_t;
#define G2L16(g, l) __builtin_amdgcn_global_load_lds((gas_t)(g), (las_t)(l), 16, 0, 0)

#if __has_builtin(__builtin_amdgcn_exp2f)
#define EX2(x) __builtin_amdgcn_exp2f(x)
#else
#define EX2(x) exp2f(x)
#endif

__device__ __forceinline__ float b2f(bf16 v) { return __bfloat162float(v); }

// pack two fp32 -> two bf16 (RNE, finite inputs), 3 int ops + merge
__device__ __forceinline__ unsigned pk2(float a, float b) {
    unsigned ua = __float_as_uint(a);
    unsigned ub = __float_as_uint(b);
    ua += 0x7FFFu + ((ua >> 16) & 1u);
    ub += 0x7FFFu + ((ub >> 16) & 1u);
    return (ua >> 16) | (ub & 0xFFFF0000u);
}

// bijective XCD swizzle for linear block id (nwg % 8 == 0)
__device__ __forceinline__ int xcd_swz(int lid, int nwg) {
    return (lid & 7) * (nwg >> 3) + (lid >> 3);
}

// ---------------------------------------------------------------------------
// K-1: X fp32 -> bf16 (one-shot; removes cvt from the qkv K-loop)
// ---------------------------------------------------------------------------
__global__ __launch_bounds__(256) void conv_x(const float* __restrict__ X,
                                              bf16* __restrict__ Xb)
{
    size_t i = ((size_t)blockIdx.x * 256 + threadIdx.x) * 8;
    float4 lo = *(const float4*)&X[i];
    float4 hi = *(const float4*)&X[i + 4];
    uint4 u;
    u.x = pk2(lo.x, lo.y); u.y = pk2(lo.z, lo.w);
    u.z = pk2(hi.x, hi.y); u.w = pk2(hi.z, hi.w);
    *(uint4*)&Xb[i] = u;
}

// ---------------------------------------------------------------------------
// K0: convert + transpose weights: W [K][N] fp32 -> WT [N][K] bf16.
// ---------------------------------------------------------------------------
__global__ __launch_bounds__(256) void conv_wT(const float* __restrict__ W,
                                               bf16* __restrict__ WT,
                                               int Kdim, int Ndim)
{
    __shared__ bf16 T[64][72];
    const int tid = threadIdx.x;
    const int n0 = blockIdx.x * 64, k0 = blockIdx.y * 64;
    const int kr = tid >> 4, nc = (tid & 15) * 4;
    #pragma unroll
    for (int p = 0; p < 4; ++p) {
        float4 v = *(const float4*)&W[(size_t)(k0 + kr + p * 16) * Ndim + n0 + nc];
        T[nc + 0][kr + p * 16] = __float2bfloat16(v.x);
        T[nc + 1][kr + p * 16] = __float2bfloat16(v.y);
        T[nc + 2][kr + p * 16] = __float2bfloat16(v.z);
        T[nc + 3][kr + p * 16] = __float2bfloat16(v.w);
    }
    __syncthreads();
    const int nr = tid >> 2, kc = (tid & 3) * 16;
    *(bf16x8*)&WT[(size_t)(n0 + nr) * Kdim + k0 + kc]     = *(const bf16x8*)&T[nr][kc];
    *(bf16x8*)&WT[(size_t)(n0 + nr) * Kdim + k0 + kc + 8] = *(const bf16x8*)&T[nr][kc + 8];
}

// ---------------------------------------------------------------------------
// qkv epilogue shared by both variants
// ---------------------------------------------------------------------------
__device__ __forceinline__ void qkv_epilogue(
    const f32x4 acc[4][4], const float* __restrict__ B1,
    bf16* __restrict__ Qp, bf16* __restrict__ Kp, bf16* __restrict__ Vt,
    int n0, int m0, int wm, int wn, int quad, int col)
{
    const int which = n0 >> 10;          // 0=q 1=k 2=v
    const int bb = m0 >> 11;
    if (which == 2) {
        #pragma unroll
        for (int i = 0; i < 4; ++i) {
            int s = (m0 & (S_ - 1)) + wm * 64 + i * 16 + quad * 4;
            #pragma unroll
            for (int j = 0; j < 4; ++j) {
                int n = n0 + wn * 64 + j * 16 + col;
                int h = (n >> 6) & 15, d = n & 63;
                float bv = B1[n];
                uint2 t;
                t.x = pk2(acc[i][j][0] + bv, acc[i][j][1] + bv);
                t.y = pk2(acc[i][j][2] + bv, acc[i][j][3] + bv);
                *(uint2*)&Vt[(((size_t)(bb * NH_ + h)) * DK_ + d) * S_ + s] = t;
            }
        }
    } else {
        bf16* dst = which ? Kp : Qp;
        const float sc = which ? 1.0f : SCALE_Q;
        #pragma unroll
        for (int i = 0; i < 4; ++i) {
            #pragma unroll
            for (int r = 0; r < 4; ++r) {
                int s = (m0 & (S_ - 1)) + wm * 64 + i * 16 + quad * 4 + r;
                #pragma unroll
                for (int j = 0; j < 4; ++j) {
                    int n = n0 + wn * 64 + j * 16 + col;
                    int h = (n >> 6) & 15, d = n & 63;
                    dst[(((size_t)(bb * NH_ + h)) * S_ + s) * DK_ + d] =
                        __float2bfloat16((acc[i][j][r] + B1[n]) * sc);
                }
            }
        }
    }
}

// ---------------------------------------------------------------------------
// K1-fast: qkv = Xbf @ W1 + b1, pure m97 (G2L16 both operands), XCD-swizzled.
// ---------------------------------------------------------------------------
__global__ __launch_bounds__(256) void gemm_qkv_mfma2(
    const bf16* __restrict__ Xb, const bf16* __restrict__ W1T,
    const float* __restrict__ B1,
    bf16* __restrict__ Qp, bf16* __restrict__ Kp, bf16* __restrict__ Vt)
{
    __shared__ bf16 As[128 * 32];
    __shared__ bf16 Bs[128 * 32];

    const int tid = threadIdx.x;
    const int lane = tid & 63, wv = tid >> 6;
    const int col = lane & 15, quad = lane >> 4;
    const int wm = wv >> 1, wn = wv & 1;
    const int lid = blockIdx.x + blockIdx.y * gridDim.x;
    const int vid = xcd_swz(lid, gridDim.x * gridDim.y);
    const int n0 = (vid % gridDim.x) * 128, m0 = (vid / gridDim.x) * 128;

    f32x4 acc[4][4] = {};

    const bf16* Ag = Xb  + (size_t)m0 * K_;
    const bf16* Bg = W1T + (size_t)n0 * K_;

    for (int k0 = 0; k0 < K_; k0 += 32) {
        #pragma unroll
        for (int h = 0; h < 2; ++h) {
            int idx = tid + h * 256;
            int row = idx >> 2, c = (idx & 3) * 8;
            G2L16(Ag + (size_t)row * K_ + k0 + c, As + (size_t)idx * 8);
            G2L16(Bg + (size_t)row * K_ + k0 + c, Bs + (size_t)idx * 8);
        }
        __syncthreads();

        bf16x8 af[4], bfr[4];
        #pragma unroll
        for (int i = 0; i < 4; ++i)
            af[i] = *(const bf16x8*)&As[(wm * 64 + i * 16 + col) * 32 + quad * 8];
        #pragma unroll
        for (int j = 0; j < 4; ++j)
            bfr[j] = *(const bf16x8*)&Bs[(wn * 64 + j * 16 + col) * 32 + quad * 8];

        #pragma unroll
        for (int i = 0; i < 4; ++i)
            #pragma unroll
            for (int j = 0; j < 4; ++j)
                acc[i][j] = __builtin_amdgcn_mfma_f32_16x16x32_bf16(af[i], bfr[j], acc[i][j], 0, 0, 0);
        __syncthreads();
    }
    qkv_epilogue(acc, B1, Qp, Kp, Vt, n0, m0, wm, wn, quad, col);
}

// ---------------------------------------------------------------------------
// K1-fallback: qkv with in-loop fp32->bf16 A conversion, XCD-swizzled.
// ---------------------------------------------------------------------------
__global__ __launch_bounds__(256) void gemm_qkv_mfma(
    const float* __restrict__ X, const bf16* __restrict__ W1T,
    const float* __restrict__ B1,
    bf16* __restrict__ Qp, bf16* __restrict__ Kp, bf16* __restrict__ Vt)
{
    __shared__ bf16 As[128 * 32];
    __shared__ bf16 Bs[128 * 32];

    const int tid = threadIdx.x;
    const int lane = tid & 63, wv = tid >> 6;
    const int col = lane & 15, quad = lane >> 4;
    const int wm = wv >> 1, wn = wv & 1;
    const int lid = blockIdx.x + blockIdx.y * gridDim.x;
    const int vid = xcd_swz(lid, gridDim.x * gridDim.y);
    const int n0 = (vid % gridDim.x) * 128, m0 = (vid / gridDim.x) * 128;

    f32x4 acc[4][4] = {};

    const float* Ag = X   + (size_t)m0 * K_;
    const bf16*  Bg = W1T + (size_t)n0 * K_;

    for (int k0 = 0; k0 < K_; k0 += 32) {
        #pragma unroll
        for (int h = 0; h < 2; ++h) {
            int idx = tid + h * 256;
            int row = idx >> 2, c = (idx & 3) * 8;
            G2L16(Bg + (size_t)row * K_ + k0 + c, Bs + (size_t)idx * 8);
        }
        #pragma unroll
        for (int h = 0; h < 2; ++h) {
            int idx = tid + h * 256;
            int row = idx >> 2, c = (idx & 3) * 8;
            float4 lo = *(const float4*)&Ag[(size_t)row * K_ + k0 + c];
            float4 hi = *(const float4*)&Ag[(size_t)row * K_ + k0 + c + 4];
            uint4 u;
            u.x = pk2(lo.x, lo.y); u.y = pk2(lo.z, lo.w);
            u.z = pk2(hi.x, hi.y); u.w = pk2(hi.z, hi.w);
            *(uint4*)&As[(size_t)idx * 8] = u;
        }
        __syncthreads();

        bf16x8 af[4], bfr[4];
        #pragma unroll
        for (int i = 0; i < 4; ++i)
            af[i] = *(const bf16x8*)&As[(wm * 64 + i * 16 + col) * 32 + quad * 8];
        #pragma unroll
        for (int j = 0; j < 4; ++j)
            bfr[j] = *(const bf16x8*)&Bs[(wn * 64 + j * 16 + col) * 32 + quad * 8];

        #pragma unroll
        for (int i = 0; i < 4; ++i)
            #pragma unroll
            for (int j = 0; j < 4; ++j)
                acc[i][j] = __builtin_amdgcn_mfma_f32_16x16x32_bf16(af[i], bfr[j], acc[i][j], 0, 0, 0);
        __syncthreads();
    }
    qkv_epilogue(acc, B1, Qp, Kp, Vt, n0, m0, wm, wn, quad, col);
}

// ---------------------------------------------------------------------------
// K2: transposed-dataflow MFMA flash attention, 2 q-subtiles per wave,
// V-fragments DIRECT from global (VMEM pipe; L2-resident via XCD swizzle).
// Block = 256 threads (4 waves), 128 q-rows; wave owns 32 rows (2 x 16).
//   S^T = K*Q^T  (A = Ks rows — loaded ONCE, used for both q-sets)
//   P = exp2(S^T) (raw v_exp_f32 + manual-RNE pk2) -> Ps LDS (per-wave)
//   O^T = Vt*P^T (A = V-frags from global registers, B = Ps b128 reads)
//   l = ones*P^T on the MFMA pipe, col-indexed for the epilogue.
// LDS 27.6KB (Ks 9.2 + Ps 18.4); Vs eliminated.
// ---------------------------------------------------------------------------
__global__ __launch_bounds__(256, 4) void attn_mfma(
    const bf16* __restrict__ Q, const bf16* __restrict__ K,
    const bf16* __restrict__ Vt, bf16* __restrict__ CTX)
{
    __shared__ bf16 Ks[64][72];         // [c][d]
    __shared__ bf16 Ps[4][2][16][72];   // per-wave, per-q-set P [r][c]

    const int tid  = threadIdx.x;
    const int wv   = tid >> 6;       // 0..3
    const int lane = tid & 63;
    const int col  = lane & 15;
    const int quad = lane >> 4;

    // bijective XCD swizzle: all 16 q-tiles of a bh land on one XCD
    const int lid = blockIdx.x + (blockIdx.y << 4);    // gridDim.x == 16
    const int vid = (lid & 7) * 128 + (lid >> 3);
    const int bh = vid >> 4;
    const int q0 = (vid & 15) * 128;

    const bf16* Qg  = Q  + (size_t)bh * S_ * DK_;
    const bf16* Kg  = K  + (size_t)bh * S_ * DK_;
    const bf16* Vtg = Vt + (size_t)bh * DK_ * S_;

    const short oneb = (short)0x3F80;
    const bf16x8 ones = {oneb, oneb, oneb, oneb, oneb, oneb, oneb, oneb};

    // Q fragments (B operand): lane(col) holds q-row q0 + wv*32 + qs*16 + col
    bf16x8 qf[2][2];
    #pragma unroll
    for (int qs = 0; qs < 2; ++qs) {
        const int qrow = q0 + wv * 32 + qs * 16 + col;
        qf[qs][0] = *(const bf16x8*)&Qg[(size_t)qrow * DK_ + quad * 8];
        qf[qs][1] = *(const bf16x8*)&Qg[(size_t)qrow * DK_ + 32 + quad * 8];
    }

    f32x4 o[2][4] = {};                 // O^T, d-subtiles per q-set
    f32x4 l_acc[2] = {};                // row sums, col-indexed

    const int sr = tid >> 2;            // staging row 0..63 (256 threads)
    const int e0 = (tid & 3) * 16;      // 16 bf16 (2 x b128) per thread

    // per-lane V-frag base: row (d) = ds*16+col, k offset quad*8
    const bf16* Vrow = Vtg + (size_t)col * S_ + quad * 8;

    // prefetch K tile 0
    bf16x8 kreg0 = *(const bf16x8*)&Kg[(size_t)sr * DK_ + e0];
    bf16x8 kreg1 = *(const bf16x8*)&Kg[(size_t)sr * DK_ + e0 + 8];

    for (int kt = 0; kt < S_ / 64; ++kt) {
        *(bf16x8*)&Ks[sr][e0]     = kreg0;
        *(bf16x8*)&Ks[sr][e0 + 8] = kreg1;
        __syncthreads();

        // V-fragments for THIS kt, direct from global (issued early; QK^T +
        // exp below hides the L2-hit latency). Coalesced: 16x64B lines/instr.
        bf16x8 vf[4][2];
        #pragma unroll
        for (int ds = 0; ds < 4; ++ds) {
            const bf16* vb = Vrow + (size_t)(ds * 16) * S_ + kt * 64;
            vf[ds][0] = *(const bf16x8*)&vb[0];
            vf[ds][1] = *(const bf16x8*)&vb[32];
        }

        if (kt + 1 < S_ / 64) {
            kreg0 = *(const bf16x8*)&Kg[(size_t)((kt + 1) * 64 + sr) * DK_ + e0];
            kreg1 = *(const bf16x8*)&Kg[(size_t)((kt + 1) * 64 + sr) * DK_ + e0 + 8];
        }

        // S^T = K Q^T: K-fragments loaded once, two MFMAs (one per q-set).
        #pragma unroll
        for (int cs = 0; cs < 4; ++cs) {
            const bf16* kb = &Ks[cs * 16 + col][0];
            bf16x8 ka0 = *(const bf16x8*)&kb[quad * 8];
            bf16x8 ka1 = *(const bf16x8*)&kb[32 + quad * 8];
            #pragma unroll
            for (int qs = 0; qs < 2; ++qs) {
                f32x4 a = {0.f, 0.f, 0.f, 0.f};
                a = __builtin_amdgcn_mfma_f32_16x16x32_bf16(ka0, qf[qs][0], a, 0, 0, 0);
                a = __builtin_amdgcn_mfma_f32_16x16x32_bf16(ka1, qf[qs][1], a, 0, 0, 0);
                uint2 p;
                p.x = pk2(EX2(a[0]), EX2(a[1]));
                p.y = pk2(EX2(a[2]), EX2(a[3]));
                *(uint2*)&Ps[wv][qs][col][cs * 16 + quad * 4] = p;
            }
        }

        // read P as B-frags (same wave wrote it; per-wave buffer, no barrier)
        bf16x8 pf[2][2];
        #pragma unroll
        for (int qs = 0; qs < 2; ++qs) {
            pf[qs][0] = *(const bf16x8*)&Ps[wv][qs][col][quad * 8];
            pf[qs][1] = *(const bf16x8*)&Ps[wv][qs][col][32 + quad * 8];
            // l += 1^T P (matrix pipe; every reg holds l[col])
            l_acc[qs] = __builtin_amdgcn_mfma_f32_16x16x32_bf16(ones, pf[qs][0], l_acc[qs], 0, 0, 0);
            l_acc[qs] = __builtin_amdgcn_mfma_f32_16x16x32_bf16(ones, pf[qs][1], l_acc[qs], 0, 0, 0);
        }

        // O^T += Vt P^T: V-fragments from registers (global-loaded).
        #pragma unroll
        for (int ds = 0; ds < 4; ++ds) {
            #pragma unroll
            for (int qs = 0; qs < 2; ++qs) {
                o[qs][ds] = __builtin_amdgcn_mfma_f32_16x16x32_bf16(vf[ds][0], pf[qs][0], o[qs][ds], 0, 0, 0);
                o[qs][ds] = __builtin_amdgcn_mfma_f32_16x16x32_bf16(vf[ds][1], pf[qs][1], o[qs][ds], 0, 0, 0);
            }
        }
        __syncthreads();
    }

    // epilogue: O^T C-layout -> 4 contiguous d per lane -> packed 8B stores
    const int b = bh >> 4, h = bh & 15;
    #pragma unroll
    for (int qs = 0; qs < 2; ++qs) {
        const float inv = 1.f / l_acc[qs][0];
        const int srow = q0 + wv * 32 + qs * 16 + col;
        bf16* crow = CTX + ((size_t)(b * S_ + srow)) * H_ + h * DK_;
        #pragma unroll
        for (int ds = 0; ds < 4; ++ds) {
            uint2 t;
            t.x = pk2(o[qs][ds][0] * inv, o[qs][ds][1] * inv);
            t.y = pk2(o[qs][ds][2] * inv, o[qs][ds][3] * inv);
            *(uint2*)&crow[ds * 16 + quad * 4] = t;
        }
    }
}

// ---------------------------------------------------------------------------
// K3: out = ctx @ W2 + b2 (MFMA), XCD-swizzled.
// ---------------------------------------------------------------------------
__global__ __launch_bounds__(256) void gemm_out_mfma(
    const bf16* __restrict__ Cx, const bf16* __restrict__ W2T,
    const float* __restrict__ B2, float* __restrict__ OUT)
{
    __shared__ bf16 As[128 * 32];
    __shared__ bf16 Bs[128 * 32];

    const int tid = threadIdx.x;
    const int lane = tid & 63, wv = tid >> 6;
    const int col = lane & 15, quad = lane >> 4;
    const int wm = wv >> 1, wn = wv & 1;
    const int lid = blockIdx.x + blockIdx.y * gridDim.x;
    const int vid = xcd_swz(lid, gridDim.x * gridDim.y);
    const int n0 = (vid % gridDim.x) * 128, m0 = (vid / gridDim.x) * 128;

    f32x4 acc[4][4] = {};

    const bf16* Ag = Cx  + (size_t)m0 * K_;
    const bf16* Bg = W2T + (size_t)n0 * K_;

    for (int k0 = 0; k0 < K_; k0 += 32) {
        #pragma unroll
        for (int h = 0; h < 2; ++h) {
            int idx = tid + h * 256;
            int row = idx >> 2, c = (idx & 3) * 8;
            G2L16(Ag + (size_t)row * K_ + k0 + c, As + (size_t)idx * 8);
            G2L16(Bg + (size_t)row * K_ + k0 + c, Bs + (size_t)idx * 8);
        }
        __syncthreads();

        bf16x8 af[4], bfr[4];
        #pragma unroll
        for (int i = 0; i < 4; ++i)
            af[i] = *(const bf16x8*)&As[(wm * 64 + i * 16 + col) * 32 + quad * 8];
        #pragma unroll
        for (int j = 0; j < 4; ++j)
            bfr[j] = *(const bf16x8*)&Bs[(wn * 64 + j * 16 + col) * 32 + quad * 8];

        #pragma unroll
        for (int i = 0; i < 4; ++i)
            #pragma unroll
            for (int j = 0; j < 4; ++j)
                acc[i][j] = __builtin_amdgcn_mfma_f32_16x16x32_bf16(af[i], bfr[j], acc[i][j], 0, 0, 0);
        __syncthreads();
    }

    #pragma unroll
    for (int i = 0; i < 4; ++i) {
        #pragma unroll
        for (int r = 0; r < 4; ++r) {
            int m = m0 + wm * 64 + i * 16 + quad * 4 + r;
            #pragma unroll
            for (int j = 0; j < 4; ++j) {
                int n = n0 + wn * 64 + j * 16 + col;
                OUT[(size_t)m * H_ + n] = acc[i][j][r] + B2[n];
            }
        }
    }
}

// ---------------------------------------------------------------------------
extern "C" void kernel_launch(void* const* d_in, const int* in_sizes, int n_in,
                              void* d_out, int out_size, void* d_ws, size_t ws_size,
                              hipStream_t stream)
{
    const float* X  = (const float*)d_in[0];
    const float* W1 = (const float*)d_in[1];
    const float* B1 = (const float*)d_in[2];
    const float* W2 = (const float*)d_in[3];
    const float* B2 = (const float*)d_in[4];
    float* OUT = (float*)d_out;

    const size_t QE = (size_t)B_ * NH_ * S_ * DK_;   // 8,388,608
    bf16* Qw  = (bf16*)d_ws;
    bf16* Kw  = Qw + QE;
    bf16* Vw  = Kw + QE;        // transposed [bh][d][s]
    bf16* Rw  = Vw + QE;        // W1T during qkv, ctx afterwards
    bf16* W1T = Rw;
    bf16* Cw  = Rw;
    bf16* W2T = Qw;             // overlays Q (dead after attn)
    bf16* Xb  = Rw + QE;        // only if ws permits (5*QE elems total)

    const bool fast = ws_size >= 5 * QE * sizeof(bf16);

    conv_wT<<<dim3(N1_ / 64, K_ / 64), 256, 0, stream>>>(W1, W1T, K_, N1_);
    if (fast) {
        conv_x<<<dim3((int)(QE / (256 * 8))), 256, 0, stream>>>(X, Xb);
        gemm_qkv_mfma2<<<dim3(N1_ / 128, M_ / 128), 256, 0, stream>>>(Xb, W1T, B1, Qw, Kw, Vw);
    } else {
        gemm_qkv_mfma<<<dim3(N1_ / 128, M_ / 128), 256, 0, stream>>>(X, W1T, B1, Qw, Kw, Vw);
    }
    attn_mfma<<<dim3(S_ / 128, B_ * NH_), 256, 0, stream>>>(Qw, Kw, Vw, Cw);
    conv_wT<<<dim3(H_ / 64, K_ / 64), 256, 0, stream>>>(W2, W2T, K_, H_);
    gemm_out_mfma<<<dim3(H_ / 128, M_ / 128), 256, 0, stream>>>(Cw, W2T, B2, OUT);
}

// Round 11
// 299.238 us; speedup vs baseline: 1.1127x; 1.1127x over previous
//
#include <hip/hip_runtime.h>
#include <hip/hip_bf16.h>

// Problem: B=4, S=2048, H=1024, NH=16, DK=64. fp32 I/O.
// R19: revert attn to R17 (R18's V-from-global was stall-bound: 16-line
// gather + 30us extra L2 traffic; MfmaUtil/VALUBusy both collapsed).
// NEW: epilogue-oriented operand swap in the GEMMs. The C-layout puts acc
// regs along the SECOND (B) operand's free dim; Q/K and OUT want
// n-contiguous stores. For Q/K blocks and for the out GEMM we compute
// mfma(B,A) (bit-identical: products commute, K-tree order fixed), so each
// lane holds 4 consecutive n -> Q/K write d-contiguous uint2 (16 stores vs
// 64 scalar), OUT writes float4 (16 vs 64). V block keeps the original
// orientation (s-contiguous uint2 already optimal).
// Keeps: raw v_exp_f32 (R11), bijective XCD swizzle everywhere (R12/R17).

typedef __hip_bfloat16 bf16;
typedef __attribute__((ext_vector_type(8))) short bf16x8;  // 8 bf16 = 4 VGPRs
typedef __attribute__((ext_vector_type(4))) float f32x4;

#define B_   4
#define S_   2048
#define H_   1024
#define NH_  16
#define DK_  64
#define M_   8192   // B_*S_
#define N1_  3072
#define K_   1024

#define SCALE_Q 0.18033688f   // 0.125 * log2(e): softmax in exp2 domain

typedef const __attribute__((address_space(1))) void* gas_t;
typedef __attribute__((address_space(3))) void* las_t;
#define G2L16(g, l) __builtin_amdgcn_global_load_lds((gas_t)(g), (las_t)(l), 16, 0, 0)

#if __has_builtin(__builtin_amdgcn_exp2f)
#define EX2(x) __builtin_amdgcn_exp2f(x)
#else
#define EX2(x) exp2f(x)
#endif

__device__ __forceinline__ float b2f(bf16 v) { return __bfloat162float(v); }

// pack two fp32 -> two bf16 (RNE, finite inputs), 3 int ops + merge
__device__ __forceinline__ unsigned pk2(float a, float b) {
    unsigned ua = __float_as_uint(a);
    unsigned ub = __float_as_uint(b);
    ua += 0x7FFFu + ((ua >> 16) & 1u);
    ub += 0x7FFFu + ((ub >> 16) & 1u);
    return (ua >> 16) | (ub & 0xFFFF0000u);
}

// bijective XCD swizzle for linear block id (nwg % 8 == 0)
__device__ __forceinline__ int xcd_swz(int lid, int nwg) {
    return (lid & 7) * (nwg >> 3) + (lid >> 3);
}

// ---------------------------------------------------------------------------
// K-1: X fp32 -> bf16 (one-shot; removes cvt from the qkv K-loop)
// ---------------------------------------------------------------------------
__global__ __launch_bounds__(256) void conv_x(const float* __restrict__ X,
                                              bf16* __restrict__ Xb)
{
    size_t i = ((size_t)blockIdx.x * 256 + threadIdx.x) * 8;
    float4 lo = *(const float4*)&X[i];
    float4 hi = *(const float4*)&X[i + 4];
    uint4 u;
    u.x = pk2(lo.x, lo.y); u.y = pk2(lo.z, lo.w);
    u.z = pk2(hi.x, hi.y); u.w = pk2(hi.z, hi.w);
    *(uint4*)&Xb[i] = u;
}

// ---------------------------------------------------------------------------
// K0: convert + transpose weights: W [K][N] fp32 -> WT [N][K] bf16.
// ---------------------------------------------------------------------------
__global__ __launch_bounds__(256) void conv_wT(const float* __restrict__ W,
                                               bf16* __restrict__ WT,
                                               int Kdim, int Ndim)
{
    __shared__ bf16 T[64][72];
    const int tid = threadIdx.x;
    const int n0 = blockIdx.x * 64, k0 = blockIdx.y * 64;
    const int kr = tid >> 4, nc = (tid & 15) * 4;
    #pragma unroll
    for (int p = 0; p < 4; ++p) {
        float4 v = *(const float4*)&W[(size_t)(k0 + kr + p * 16) * Ndim + n0 + nc];
        T[nc + 0][kr + p * 16] = __float2bfloat16(v.x);
        T[nc + 1][kr + p * 16] = __float2bfloat16(v.y);
        T[nc + 2][kr + p * 16] = __float2bfloat16(v.z);
        T[nc + 3][kr + p * 16] = __float2bfloat16(v.w);
    }
    __syncthreads();
    const int nr = tid >> 2, kc = (tid & 3) * 16;
    *(bf16x8*)&WT[(size_t)(n0 + nr) * Kdim + k0 + kc]     = *(const bf16x8*)&T[nr][kc];
    *(bf16x8*)&WT[(size_t)(n0 + nr) * Kdim + k0 + kc + 8] = *(const bf16x8*)&T[nr][kc + 8];
}

// ---------------------------------------------------------------------------
// qkv epilogues.
//  V-block (original orientation): acc regs along m (s-direction) -> uint2
//  along s into Vt[bh][d][s].
//  Q/K-block (swapped operands):   acc regs along n (d-direction) -> uint2
//  along d into {Q,K}[bh][s][d].
// ---------------------------------------------------------------------------
__device__ __forceinline__ void qkv_epilogue_v(
    const f32x4 acc[4][4], const float* __restrict__ B1,
    bf16* __restrict__ Vt, int n0, int m0, int wm, int wn, int quad, int col)
{
    const int bb = m0 >> 11;
    #pragma unroll
    for (int i = 0; i < 4; ++i) {
        int s = (m0 & (S_ - 1)) + wm * 64 + i * 16 + quad * 4;
        #pragma unroll
        for (int j = 0; j < 4; ++j) {
            int n = n0 + wn * 64 + j * 16 + col;
            int h = (n >> 6) & 15, d = n & 63;
            float bv = B1[n];
            uint2 t;
            t.x = pk2(acc[i][j][0] + bv, acc[i][j][1] + bv);
            t.y = pk2(acc[i][j][2] + bv, acc[i][j][3] + bv);
            *(uint2*)&Vt[(((size_t)(bb * NH_ + h)) * DK_ + d) * S_ + s] = t;
        }
    }
}

__device__ __forceinline__ void qkv_epilogue_qk(
    const f32x4 acc[4][4], const float* __restrict__ B1,
    bf16* __restrict__ Qp, bf16* __restrict__ Kp,
    int which, int n0, int m0, int wm, int wn, int quad, int col)
{
    bf16* dst = which ? Kp : Qp;
    const float sc = which ? 1.0f : SCALE_Q;
    const int bb = m0 >> 11;
    #pragma unroll
    for (int i = 0; i < 4; ++i) {
        int m = m0 + wm * 64 + i * 16 + col;
        int s = m & (S_ - 1);
        #pragma unroll
        for (int j = 0; j < 4; ++j) {
            int n = n0 + wn * 64 + j * 16 + quad * 4;
            int h = (n >> 6) & 15, d = n & 63;
            float4 b = *(const float4*)&B1[n];
            uint2 t;
            t.x = pk2((acc[i][j][0] + b.x) * sc, (acc[i][j][1] + b.y) * sc);
            t.y = pk2((acc[i][j][2] + b.z) * sc, (acc[i][j][3] + b.w) * sc);
            *(uint2*)&dst[(((size_t)(bb * NH_ + h)) * S_ + s) * DK_ + d] = t;
        }
    }
}

// ---------------------------------------------------------------------------
// K1-fast: qkv = Xbf @ W1 + b1, pure m97 (G2L16 both operands), XCD-swizzled,
// epilogue-oriented operand order per block type.
// ---------------------------------------------------------------------------
__global__ __launch_bounds__(256) void gemm_qkv_mfma2(
    const bf16* __restrict__ Xb, const bf16* __restrict__ W1T,
    const float* __restrict__ B1,
    bf16* __restrict__ Qp, bf16* __restrict__ Kp, bf16* __restrict__ Vt)
{
    __shared__ bf16 As[128 * 32];
    __shared__ bf16 Bs[128 * 32];

    const int tid = threadIdx.x;
    const int lane = tid & 63, wv = tid >> 6;
    const int col = lane & 15, quad = lane >> 4;
    const int wm = wv >> 1, wn = wv & 1;
    const int lid = blockIdx.x + blockIdx.y * gridDim.x;
    const int vid = xcd_swz(lid, gridDim.x * gridDim.y);
    const int n0 = (vid % gridDim.x) * 128, m0 = (vid / gridDim.x) * 128;
    const int which = n0 >> 10;          // 0=q 1=k 2=v
    const bool vblk = (which == 2);

    f32x4 acc[4][4] = {};

    const bf16* Ag = Xb  + (size_t)m0 * K_;
    const bf16* Bg = W1T + (size_t)n0 * K_;

    for (int k0 = 0; k0 < K_; k0 += 32) {
        #pragma unroll
        for (int h = 0; h < 2; ++h) {
            int idx = tid + h * 256;
            int row = idx >> 2, c = (idx & 3) * 8;
            G2L16(Ag + (size_t)row * K_ + k0 + c, As + (size_t)idx * 8);
            G2L16(Bg + (size_t)row * K_ + k0 + c, Bs + (size_t)idx * 8);
        }
        __syncthreads();

        bf16x8 af[4], bfr[4];
        #pragma unroll
        for (int i = 0; i < 4; ++i)
            af[i] = *(const bf16x8*)&As[(wm * 64 + i * 16 + col) * 32 + quad * 8];
        #pragma unroll
        for (int j = 0; j < 4; ++j)
            bfr[j] = *(const bf16x8*)&Bs[(wn * 64 + j * 16 + col) * 32 + quad * 8];

        if (vblk) {
            #pragma unroll
            for (int i = 0; i < 4; ++i)
                #pragma unroll
                for (int j = 0; j < 4; ++j)
                    acc[i][j] = __builtin_amdgcn_mfma_f32_16x16x32_bf16(af[i], bfr[j], acc[i][j], 0, 0, 0);
        } else {
            #pragma unroll
            for (int i = 0; i < 4; ++i)
                #pragma unroll
                for (int j = 0; j < 4; ++j)
                    acc[i][j] = __builtin_amdgcn_mfma_f32_16x16x32_bf16(bfr[j], af[i], acc[i][j], 0, 0, 0);
        }
        __syncthreads();
    }
    if (vblk)
        qkv_epilogue_v(acc, B1, Vt, n0, m0, wm, wn, quad, col);
    else
        qkv_epilogue_qk(acc, B1, Qp, Kp, which, n0, m0, wm, wn, quad, col);
}

// ---------------------------------------------------------------------------
// K1-fallback: qkv with in-loop fp32->bf16 A conversion, XCD-swizzled.
// ---------------------------------------------------------------------------
__global__ __launch_bounds__(256) void gemm_qkv_mfma(
    const float* __restrict__ X, const bf16* __restrict__ W1T,
    const float* __restrict__ B1,
    bf16* __restrict__ Qp, bf16* __restrict__ Kp, bf16* __restrict__ Vt)
{
    __shared__ bf16 As[128 * 32];
    __shared__ bf16 Bs[128 * 32];

    const int tid = threadIdx.x;
    const int lane = tid & 63, wv = tid >> 6;
    const int col = lane & 15, quad = lane >> 4;
    const int wm = wv >> 1, wn = wv & 1;
    const int lid = blockIdx.x + blockIdx.y * gridDim.x;
    const int vid = xcd_swz(lid, gridDim.x * gridDim.y);
    const int n0 = (vid % gridDim.x) * 128, m0 = (vid / gridDim.x) * 128;
    const int which = n0 >> 10;
    const bool vblk = (which == 2);

    f32x4 acc[4][4] = {};

    const float* Ag = X   + (size_t)m0 * K_;
    const bf16*  Bg = W1T + (size_t)n0 * K_;

    for (int k0 = 0; k0 < K_; k0 += 32) {
        #pragma unroll
        for (int h = 0; h < 2; ++h) {
            int idx = tid + h * 256;
            int row = idx >> 2, c = (idx & 3) * 8;
            G2L16(Bg + (size_t)row * K_ + k0 + c, Bs + (size_t)idx * 8);
        }
        #pragma unroll
        for (int h = 0; h < 2; ++h) {
            int idx = tid + h * 256;
            int row = idx >> 2, c = (idx & 3) * 8;
            float4 lo = *(const float4*)&Ag[(size_t)row * K_ + k0 + c];
            float4 hi = *(const float4*)&Ag[(size_t)row * K_ + k0 + c + 4];
            uint4 u;
            u.x = pk2(lo.x, lo.y); u.y = pk2(lo.z, lo.w);
            u.z = pk2(hi.x, hi.y); u.w = pk2(hi.z, hi.w);
            *(uint4*)&As[(size_t)idx * 8] = u;
        }
        __syncthreads();

        bf16x8 af[4], bfr[4];
        #pragma unroll
        for (int i = 0; i < 4; ++i)
            af[i] = *(const bf16x8*)&As[(wm * 64 + i * 16 + col) * 32 + quad * 8];
        #pragma unroll
        for (int j = 0; j < 4; ++j)
            bfr[j] = *(const bf16x8*)&Bs[(wn * 64 + j * 16 + col) * 32 + quad * 8];

        if (vblk) {
            #pragma unroll
            for (int i = 0; i < 4; ++i)
                #pragma unroll
                for (int j = 0; j < 4; ++j)
                    acc[i][j] = __builtin_amdgcn_mfma_f32_16x16x32_bf16(af[i], bfr[j], acc[i][j], 0, 0, 0);
        } else {
            #pragma unroll
            for (int i = 0; i < 4; ++i)
                #pragma unroll
                for (int j = 0; j < 4; ++j)
                    acc[i][j] = __builtin_amdgcn_mfma_f32_16x16x32_bf16(bfr[j], af[i], acc[i][j], 0, 0, 0);
        }
        __syncthreads();
    }
    if (vblk)
        qkv_epilogue_v(acc, B1, Vt, n0, m0, wm, wn, quad, col);
    else
        qkv_epilogue_qk(acc, B1, Qp, Kp, which, n0, m0, wm, wn, quad, col);
}

// ---------------------------------------------------------------------------
// K2: transposed-dataflow MFMA flash attention, 2 q-subtiles per wave.
// (R17's verified kernel, 102us.)
// ---------------------------------------------------------------------------
__global__ __launch_bounds__(256, 4) void attn_mfma(
    const bf16* __restrict__ Q, const bf16* __restrict__ K,
    const bf16* __restrict__ Vt, bf16* __restrict__ CTX)
{
    __shared__ bf16 Ks[64][72];         // [c][d]
    __shared__ bf16 Vs[64][72];         // [d][c]
    __shared__ bf16 Ps[4][2][16][72];   // per-wave, per-q-set P [r][c]

    const int tid  = threadIdx.x;
    const int wv   = tid >> 6;       // 0..3
    const int lane = tid & 63;
    const int col  = lane & 15;
    const int quad = lane >> 4;

    // bijective XCD swizzle: all 16 q-tiles of a bh land on one XCD
    const int lid = blockIdx.x + (blockIdx.y << 4);    // gridDim.x == 16
    const int vid = (lid & 7) * 128 + (lid >> 3);
    const int bh = vid >> 4;
    const int q0 = (vid & 15) * 128;

    const bf16* Qg  = Q  + (size_t)bh * S_ * DK_;
    const bf16* Kg  = K  + (size_t)bh * S_ * DK_;
    const bf16* Vtg = Vt + (size_t)bh * DK_ * S_;

    const short oneb = (short)0x3F80;
    const bf16x8 ones = {oneb, oneb, oneb, oneb, oneb, oneb, oneb, oneb};

    // Q fragments (B operand): lane(col) holds q-row q0 + wv*32 + qs*16 + col
    bf16x8 qf[2][2];
    #pragma unroll
    for (int qs = 0; qs < 2; ++qs) {
        const int qrow = q0 + wv * 32 + qs * 16 + col;
        qf[qs][0] = *(const bf16x8*)&Qg[(size_t)qrow * DK_ + quad * 8];
        qf[qs][1] = *(const bf16x8*)&Qg[(size_t)qrow * DK_ + 32 + quad * 8];
    }

    f32x4 o[2][4] = {};                 // O^T, d-subtiles per q-set
    f32x4 l_acc[2] = {};                // row sums, col-indexed

    const int sr = tid >> 2;            // staging row 0..63 (256 threads)
    const int e0 = (tid & 3) * 16;      // 16 bf16 (2 x b128) per thread per buf

    // prefetch tile 0
    bf16x8 kreg0 = *(const bf16x8*)&Kg[(size_t)sr * DK_ + e0];
    bf16x8 kreg1 = *(const bf16x8*)&Kg[(size_t)sr * DK_ + e0 + 8];
    bf16x8 vreg0 = *(const bf16x8*)&Vtg[(size_t)sr * S_ + e0];
    bf16x8 vreg1 = *(const bf16x8*)&Vtg[(size_t)sr * S_ + e0 + 8];

    for (int kt = 0; kt < S_ / 64; ++kt) {
        *(bf16x8*)&Ks[sr][e0]     = kreg0;
        *(bf16x8*)&Ks[sr][e0 + 8] = kreg1;
        *(bf16x8*)&Vs[sr][e0]     = vreg0;
        *(bf16x8*)&Vs[sr][e0 + 8] = vreg1;
        __syncthreads();

        if (kt + 1 < S_ / 64) {
            kreg0 = *(const bf16x8*)&Kg[(size_t)((kt + 1) * 64 + sr) * DK_ + e0];
            kreg1 = *(const bf16x8*)&Kg[(size_t)((kt + 1) * 64 + sr) * DK_ + e0 + 8];
            vreg0 = *(const bf16x8*)&Vtg[(size_t)sr * S_ + (kt + 1) * 64 + e0];
            vreg1 = *(const bf16x8*)&Vtg[(size_t)sr * S_ + (kt + 1) * 64 + e0 + 8];
        }

        // S^T = K Q^T: K-fragments loaded once, two MFMAs (one per q-set).
        #pragma unroll
        for (int cs = 0; cs < 4; ++cs) {
            const bf16* kb = &Ks[cs * 16 + col][0];
            bf16x8 ka0 = *(const bf16x8*)&kb[quad * 8];
            bf16x8 ka1 = *(const bf16x8*)&kb[32 + quad * 8];
            #pragma unroll
            for (int qs = 0; qs < 2; ++qs) {
                f32x4 a = {0.f, 0.f, 0.f, 0.f};
                a = __builtin_amdgcn_mfma_f32_16x16x32_bf16(ka0, qf[qs][0], a, 0, 0, 0);
                a = __builtin_amdgcn_mfma_f32_16x16x32_bf16(ka1, qf[qs][1], a, 0, 0, 0);
                uint2 p;
                p.x = pk2(EX2(a[0]), EX2(a[1]));
                p.y = pk2(EX2(a[2]), EX2(a[3]));
                *(uint2*)&Ps[wv][qs][col][cs * 16 + quad * 4] = p;
            }
        }

        // read P as B-frags (same wave wrote it; per-wave buffer, no barrier)
        bf16x8 pf[2][2];
        #pragma unroll
        for (int qs = 0; qs < 2; ++qs) {
            pf[qs][0] = *(const bf16x8*)&Ps[wv][qs][col][quad * 8];
            pf[qs][1] = *(const bf16x8*)&Ps[wv][qs][col][32 + quad * 8];
            // l += 1^T P (matrix pipe; every reg holds l[col])
            l_acc[qs] = __builtin_amdgcn_mfma_f32_16x16x32_bf16(ones, pf[qs][0], l_acc[qs], 0, 0, 0);
            l_acc[qs] = __builtin_amdgcn_mfma_f32_16x16x32_bf16(ones, pf[qs][1], l_acc[qs], 0, 0, 0);
        }

        // O^T += Vt P^T: V-fragments loaded once, two MFMAs each.
        #pragma unroll
        for (int ds = 0; ds < 4; ++ds) {
            const bf16* vb = &Vs[ds * 16 + col][0];
            bf16x8 va0 = *(const bf16x8*)&vb[quad * 8];
            bf16x8 va1 = *(const bf16x8*)&vb[32 + quad * 8];
            #pragma unroll
            for (int qs = 0; qs < 2; ++qs) {
                o[qs][ds] = __builtin_amdgcn_mfma_f32_16x16x32_bf16(va0, pf[qs][0], o[qs][ds], 0, 0, 0);
                o[qs][ds] = __builtin_amdgcn_mfma_f32_16x16x32_bf16(va1, pf[qs][1], o[qs][ds], 0, 0, 0);
            }
        }
        __syncthreads();
    }

    // epilogue: O^T C-layout -> 4 contiguous d per lane -> packed 8B stores
    const int b = bh >> 4, h = bh & 15;
    #pragma unroll
    for (int qs = 0; qs < 2; ++qs) {
        const float inv = 1.f / l_acc[qs][0];
        const int srow = q0 + wv * 32 + qs * 16 + col;
        bf16* crow = CTX + ((size_t)(b * S_ + srow)) * H_ + h * DK_;
        #pragma unroll
        for (int ds = 0; ds < 4; ++ds) {
            uint2 t;
            t.x = pk2(o[qs][ds][0] * inv, o[qs][ds][1] * inv);
            t.y = pk2(o[qs][ds][2] * inv, o[qs][ds][3] * inv);
            *(uint2*)&crow[ds * 16 + quad * 4] = t;
        }
    }
}

// ---------------------------------------------------------------------------
// K3: out = ctx @ W2 + b2 (MFMA), XCD-swizzled, swapped operands ->
// n-contiguous float4 epilogue (16 stores vs 64 scalar).
// ---------------------------------------------------------------------------
__global__ __launch_bounds__(256) void gemm_out_mfma(
    const bf16* __restrict__ Cx, const bf16* __restrict__ W2T,
    const float* __restrict__ B2, float* __restrict__ OUT)
{
    __shared__ bf16 As[128 * 32];
    __shared__ bf16 Bs[128 * 32];

    const int tid = threadIdx.x;
    const int lane = tid & 63, wv = tid >> 6;
    const int col = lane & 15, quad = lane >> 4;
    const int wm = wv >> 1, wn = wv & 1;
    const int lid = blockIdx.x + blockIdx.y * gridDim.x;
    const int vid = xcd_swz(lid, gridDim.x * gridDim.y);
    const int n0 = (vid % gridDim.x) * 128, m0 = (vid / gridDim.x) * 128;

    f32x4 acc[4][4] = {};

    const bf16* Ag = Cx  + (size_t)m0 * K_;
    const bf16* Bg = W2T + (size_t)n0 * K_;

    for (int k0 = 0; k0 < K_; k0 += 32) {
        #pragma unroll
        for (int h = 0; h < 2; ++h) {
            int idx = tid + h * 256;
            int row = idx >> 2, c = (idx & 3) * 8;
            G2L16(Ag + (size_t)row * K_ + k0 + c, As + (size_t)idx * 8);
            G2L16(Bg + (size_t)row * K_ + k0 + c, Bs + (size_t)idx * 8);
        }
        __syncthreads();

        bf16x8 af[4], bfr[4];
        #pragma unroll
        for (int i = 0; i < 4; ++i)
            af[i] = *(const bf16x8*)&As[(wm * 64 + i * 16 + col) * 32 + quad * 8];
        #pragma unroll
        for (int j = 0; j < 4; ++j)
            bfr[j] = *(const bf16x8*)&Bs[(wn * 64 + j * 16 + col) * 32 + quad * 8];

        #pragma unroll
        for (int i = 0; i < 4; ++i)
            #pragma unroll
            for (int j = 0; j < 4; ++j)
                acc[i][j] = __builtin_amdgcn_mfma_f32_16x16x32_bf16(bfr[j], af[i], acc[i][j], 0, 0, 0);
        __syncthreads();
    }

    // swapped C-layout: m = col-side, n = reg-side (4 consecutive n per lane)
    #pragma unroll
    for (int i = 0; i < 4; ++i) {
        int m = m0 + wm * 64 + i * 16 + col;
        #pragma unroll
        for (int j = 0; j < 4; ++j) {
            int n = n0 + wn * 64 + j * 16 + quad * 4;
            float4 b = *(const float4*)&B2[n];
            float4 t;
            t.x = acc[i][j][0] + b.x;
            t.y = acc[i][j][1] + b.y;
            t.z = acc[i][j][2] + b.z;
            t.w = acc[i][j][3] + b.w;
            *(float4*)&OUT[(size_t)m * H_ + n] = t;
        }
    }
}

// ---------------------------------------------------------------------------
extern "C" void kernel_launch(void* const* d_in, const int* in_sizes, int n_in,
                              void* d_out, int out_size, void* d_ws, size_t ws_size,
                              hipStream_t stream)
{
    const float* X  = (const float*)d_in[0];
    const float* W1 = (const float*)d_in[1];
    const float* B1 = (const float*)d_in[2];
    const float* W2 = (const float*)d_in[3];
    const float* B2 = (const float*)d_in[4];
    float* OUT = (float*)d_out;

    const size_t QE = (size_t)B_ * NH_ * S_ * DK_;   // 8,388,608
    bf16* Qw  = (bf16*)d_ws;
    bf16* Kw  = Qw + QE;
    bf16* Vw  = Kw + QE;        // transposed [bh][d][s]
    bf16* Rw  = Vw + QE;        // W1T during qkv, ctx afterwards
    bf16* W1T = Rw;
    bf16* Cw  = Rw;
    bf16* W2T = Qw;             // overlays Q (dead after attn)
    bf16* Xb  = Rw + QE;        // only if ws permits (5*QE elems total)

    const bool fast = ws_size >= 5 * QE * sizeof(bf16);

    conv_wT<<<dim3(N1_ / 64, K_ / 64), 256, 0, stream>>>(W1, W1T, K_, N1_);
    if (fast) {
        conv_x<<<dim3((int)(QE / (256 * 8))), 256, 0, stream>>>(X, Xb);
        gemm_qkv_mfma2<<<dim3(N1_ / 128, M_ / 128), 256, 0, stream>>>(Xb, W1T, B1, Qw, Kw, Vw);
    } else {
        gemm_qkv_mfma<<<dim3(N1_ / 128, M_ / 128), 256, 0, stream>>>(X, W1T, B1, Qw, Kw, Vw);
    }
    attn_mfma<<<dim3(S_ / 128, B_ * NH_), 256, 0, stream>>>(Qw, Kw, Vw, Cw);
    conv_wT<<<dim3(H_ / 64, K_ / 64), 256, 0, stream>>>(W2, W2T, K_, H_);
    gemm_out_mfma<<<dim3(H_ / 128, M_ / 128), 256, 0, stream>>>(Cw, W2T, B2, OUT);
}

// Round 12
// 295.176 us; speedup vs baseline: 1.1281x; 1.0138x over previous
//
#include <hip/hip_runtime.h>
#include <hip/hip_bf16.h>

// Problem: B=4, S=2048, H=1024, NH=16, DK=64. fp32 I/O.
// R20: R19 with the qkv vblk branch HOISTED out of the K-loop. R19's +13us
// regression vs R17 is attributed to keeping both MFMA orientations live in
// one hot loop (code bloat / register pressure); each path now compiles as
// a tight single-orientation loop. Epilogues stay vectorized:
//  Q/K: swapped operands -> d-contiguous uint2 (16 stores vs 64 scalar)
//  V:   original orientation -> s-contiguous uint2 (unchanged)
//  OUT: swapped operands -> n-contiguous float4 (16 stores vs 64 scalar)
// attn = R17's verified 102us kernel. XCD swizzles everywhere (R12/R17).
// Numerics identical to R19 (passed at absmax 0.00195).

typedef __hip_bfloat16 bf16;
typedef __attribute__((ext_vector_type(8))) short bf16x8;  // 8 bf16 = 4 VGPRs
typedef __attribute__((ext_vector_type(4))) float f32x4;

#define B_   4
#define S_   2048
#define H_   1024
#define NH_  16
#define DK_  64
#define M_   8192   // B_*S_
#define N1_  3072
#define K_   1024

#define SCALE_Q 0.18033688f   // 0.125 * log2(e): softmax in exp2 domain

typedef const __attribute__((address_space(1))) void* gas_t;
typedef __attribute__((address_space(3))) void* las_t;
#define G2L16(g, l) __builtin_amdgcn_global_load_lds((gas_t)(g), (las_t)(l), 16, 0, 0)

#if __has_builtin(__builtin_amdgcn_exp2f)
#define EX2(x) __builtin_amdgcn_exp2f(x)
#else
#define EX2(x) exp2f(x)
#endif

__device__ __forceinline__ float b2f(bf16 v) { return __bfloat162float(v); }

// pack two fp32 -> two bf16 (RNE, finite inputs), 3 int ops + merge
__device__ __forceinline__ unsigned pk2(float a, float b) {
    unsigned ua = __float_as_uint(a);
    unsigned ub = __float_as_uint(b);
    ua += 0x7FFFu + ((ua >> 16) & 1u);
    ub += 0x7FFFu + ((ub >> 16) & 1u);
    return (ua >> 16) | (ub & 0xFFFF0000u);
}

// bijective XCD swizzle for linear block id (nwg % 8 == 0)
__device__ __forceinline__ int xcd_swz(int lid, int nwg) {
    return (lid & 7) * (nwg >> 3) + (lid >> 3);
}

// ---------------------------------------------------------------------------
// K-1: X fp32 -> bf16 (one-shot; removes cvt from the qkv K-loop)
// ---------------------------------------------------------------------------
__global__ __launch_bounds__(256) void conv_x(const float* __restrict__ X,
                                              bf16* __restrict__ Xb)
{
    size_t i = ((size_t)blockIdx.x * 256 + threadIdx.x) * 8;
    float4 lo = *(const float4*)&X[i];
    float4 hi = *(const float4*)&X[i + 4];
    uint4 u;
    u.x = pk2(lo.x, lo.y); u.y = pk2(lo.z, lo.w);
    u.z = pk2(hi.x, hi.y); u.w = pk2(hi.z, hi.w);
    *(uint4*)&Xb[i] = u;
}

// ---------------------------------------------------------------------------
// K0: convert + transpose weights: W [K][N] fp32 -> WT [N][K] bf16.
// ---------------------------------------------------------------------------
__global__ __launch_bounds__(256) void conv_wT(const float* __restrict__ W,
                                               bf16* __restrict__ WT,
                                               int Kdim, int Ndim)
{
    __shared__ bf16 T[64][72];
    const int tid = threadIdx.x;
    const int n0 = blockIdx.x * 64, k0 = blockIdx.y * 64;
    const int kr = tid >> 4, nc = (tid & 15) * 4;
    #pragma unroll
    for (int p = 0; p < 4; ++p) {
        float4 v = *(const float4*)&W[(size_t)(k0 + kr + p * 16) * Ndim + n0 + nc];
        T[nc + 0][kr + p * 16] = __float2bfloat16(v.x);
        T[nc + 1][kr + p * 16] = __float2bfloat16(v.y);
        T[nc + 2][kr + p * 16] = __float2bfloat16(v.z);
        T[nc + 3][kr + p * 16] = __float2bfloat16(v.w);
    }
    __syncthreads();
    const int nr = tid >> 2, kc = (tid & 3) * 16;
    *(bf16x8*)&WT[(size_t)(n0 + nr) * Kdim + k0 + kc]     = *(const bf16x8*)&T[nr][kc];
    *(bf16x8*)&WT[(size_t)(n0 + nr) * Kdim + k0 + kc + 8] = *(const bf16x8*)&T[nr][kc + 8];
}

// ---------------------------------------------------------------------------
// qkv epilogues.
//  V-block (original orientation): acc regs along m (s-direction) -> uint2
//  along s into Vt[bh][d][s].
//  Q/K-block (swapped operands):   acc regs along n (d-direction) -> uint2
//  along d into {Q,K}[bh][s][d].
// ---------------------------------------------------------------------------
__device__ __forceinline__ void qkv_epilogue_v(
    const f32x4 acc[4][4], const float* __restrict__ B1,
    bf16* __restrict__ Vt, int n0, int m0, int wm, int wn, int quad, int col)
{
    const int bb = m0 >> 11;
    #pragma unroll
    for (int i = 0; i < 4; ++i) {
        int s = (m0 & (S_ - 1)) + wm * 64 + i * 16 + quad * 4;
        #pragma unroll
        for (int j = 0; j < 4; ++j) {
            int n = n0 + wn * 64 + j * 16 + col;
            int h = (n >> 6) & 15, d = n & 63;
            float bv = B1[n];
            uint2 t;
            t.x = pk2(acc[i][j][0] + bv, acc[i][j][1] + bv);
            t.y = pk2(acc[i][j][2] + bv, acc[i][j][3] + bv);
            *(uint2*)&Vt[(((size_t)(bb * NH_ + h)) * DK_ + d) * S_ + s] = t;
        }
    }
}

__device__ __forceinline__ void qkv_epilogue_qk(
    const f32x4 acc[4][4], const float* __restrict__ B1,
    bf16* __restrict__ Qp, bf16* __restrict__ Kp,
    int which, int n0, int m0, int wm, int wn, int quad, int col)
{
    bf16* dst = which ? Kp : Qp;
    const float sc = which ? 1.0f : SCALE_Q;
    const int bb = m0 >> 11;
    #pragma unroll
    for (int i = 0; i < 4; ++i) {
        int m = m0 + wm * 64 + i * 16 + col;
        int s = m & (S_ - 1);
        #pragma unroll
        for (int j = 0; j < 4; ++j) {
            int n = n0 + wn * 64 + j * 16 + quad * 4;
            int h = (n >> 6) & 15, d = n & 63;
            float4 b = *(const float4*)&B1[n];
            uint2 t;
            t.x = pk2((acc[i][j][0] + b.x) * sc, (acc[i][j][1] + b.y) * sc);
            t.y = pk2((acc[i][j][2] + b.z) * sc, (acc[i][j][3] + b.w) * sc);
            *(uint2*)&dst[(((size_t)(bb * NH_ + h)) * S_ + s) * DK_ + d] = t;
        }
    }
}

// ---------------------------------------------------------------------------
// K1-fast: qkv = Xbf @ W1 + b1, pure m97 (G2L16 both operands), XCD-swizzled.
// Uniform vblk branch hoisted to kernel level: each path is a tight
// single-orientation K-loop (no dual-path register pressure).
// ---------------------------------------------------------------------------
__global__ __launch_bounds__(256) void gemm_qkv_mfma2(
    const bf16* __restrict__ Xb, const bf16* __restrict__ W1T,
    const float* __restrict__ B1,
    bf16* __restrict__ Qp, bf16* __restrict__ Kp, bf16* __restrict__ Vt)
{
    __shared__ bf16 As[128 * 32];
    __shared__ bf16 Bs[128 * 32];

    const int tid = threadIdx.x;
    const int lane = tid & 63, wv = tid >> 6;
    const int col = lane & 15, quad = lane >> 4;
    const int wm = wv >> 1, wn = wv & 1;
    const int lid = blockIdx.x + blockIdx.y * gridDim.x;
    const int vid = xcd_swz(lid, gridDim.x * gridDim.y);
    const int n0 = (vid % gridDim.x) * 128, m0 = (vid / gridDim.x) * 128;
    const int which = n0 >> 10;          // 0=q 1=k 2=v

    f32x4 acc[4][4] = {};

    const bf16* Ag = Xb  + (size_t)m0 * K_;
    const bf16* Bg = W1T + (size_t)n0 * K_;

    if (which == 2) {
        for (int k0 = 0; k0 < K_; k0 += 32) {
            #pragma unroll
            for (int h = 0; h < 2; ++h) {
                int idx = tid + h * 256;
                int row = idx >> 2, c = (idx & 3) * 8;
                G2L16(Ag + (size_t)row * K_ + k0 + c, As + (size_t)idx * 8);
                G2L16(Bg + (size_t)row * K_ + k0 + c, Bs + (size_t)idx * 8);
            }
            __syncthreads();
            bf16x8 af[4], bfr[4];
            #pragma unroll
            for (int i = 0; i < 4; ++i)
                af[i] = *(const bf16x8*)&As[(wm * 64 + i * 16 + col) * 32 + quad * 8];
            #pragma unroll
            for (int j = 0; j < 4; ++j)
                bfr[j] = *(const bf16x8*)&Bs[(wn * 64 + j * 16 + col) * 32 + quad * 8];
            #pragma unroll
            for (int i = 0; i < 4; ++i)
                #pragma unroll
                for (int j = 0; j < 4; ++j)
                    acc[i][j] = __builtin_amdgcn_mfma_f32_16x16x32_bf16(af[i], bfr[j], acc[i][j], 0, 0, 0);
            __syncthreads();
        }
        qkv_epilogue_v(acc, B1, Vt, n0, m0, wm, wn, quad, col);
    } else {
        for (int k0 = 0; k0 < K_; k0 += 32) {
            #pragma unroll
            for (int h = 0; h < 2; ++h) {
                int idx = tid + h * 256;
                int row = idx >> 2, c = (idx & 3) * 8;
                G2L16(Ag + (size_t)row * K_ + k0 + c, As + (size_t)idx * 8);
                G2L16(Bg + (size_t)row * K_ + k0 + c, Bs + (size_t)idx * 8);
            }
            __syncthreads();
            bf16x8 af[4], bfr[4];
            #pragma unroll
            for (int i = 0; i < 4; ++i)
                af[i] = *(const bf16x8*)&As[(wm * 64 + i * 16 + col) * 32 + quad * 8];
            #pragma unroll
            for (int j = 0; j < 4; ++j)
                bfr[j] = *(const bf16x8*)&Bs[(wn * 64 + j * 16 + col) * 32 + quad * 8];
            #pragma unroll
            for (int i = 0; i < 4; ++i)
                #pragma unroll
                for (int j = 0; j < 4; ++j)
                    acc[i][j] = __builtin_amdgcn_mfma_f32_16x16x32_bf16(bfr[j], af[i], acc[i][j], 0, 0, 0);
            __syncthreads();
        }
        qkv_epilogue_qk(acc, B1, Qp, Kp, which, n0, m0, wm, wn, quad, col);
    }
}

// ---------------------------------------------------------------------------
// K1-fallback: qkv with in-loop fp32->bf16 A conversion, XCD-swizzled,
// same hoisted-branch structure.
// ---------------------------------------------------------------------------
__global__ __launch_bounds__(256) void gemm_qkv_mfma(
    const float* __restrict__ X, const bf16* __restrict__ W1T,
    const float* __restrict__ B1,
    bf16* __restrict__ Qp, bf16* __restrict__ Kp, bf16* __restrict__ Vt)
{
    __shared__ bf16 As[128 * 32];
    __shared__ bf16 Bs[128 * 32];

    const int tid = threadIdx.x;
    const int lane = tid & 63, wv = tid >> 6;
    const int col = lane & 15, quad = lane >> 4;
    const int wm = wv >> 1, wn = wv & 1;
    const int lid = blockIdx.x + blockIdx.y * gridDim.x;
    const int vid = xcd_swz(lid, gridDim.x * gridDim.y);
    const int n0 = (vid % gridDim.x) * 128, m0 = (vid / gridDim.x) * 128;
    const int which = n0 >> 10;

    f32x4 acc[4][4] = {};

    const float* Ag = X   + (size_t)m0 * K_;
    const bf16*  Bg = W1T + (size_t)n0 * K_;

    if (which == 2) {
        for (int k0 = 0; k0 < K_; k0 += 32) {
            #pragma unroll
            for (int h = 0; h < 2; ++h) {
                int idx = tid + h * 256;
                int row = idx >> 2, c = (idx & 3) * 8;
                G2L16(Bg + (size_t)row * K_ + k0 + c, Bs + (size_t)idx * 8);
            }
            #pragma unroll
            for (int h = 0; h < 2; ++h) {
                int idx = tid + h * 256;
                int row = idx >> 2, c = (idx & 3) * 8;
                float4 lo = *(const float4*)&Ag[(size_t)row * K_ + k0 + c];
                float4 hi = *(const float4*)&Ag[(size_t)row * K_ + k0 + c + 4];
                uint4 u;
                u.x = pk2(lo.x, lo.y); u.y = pk2(lo.z, lo.w);
                u.z = pk2(hi.x, hi.y); u.w = pk2(hi.z, hi.w);
                *(uint4*)&As[(size_t)idx * 8] = u;
            }
            __syncthreads();
            bf16x8 af[4], bfr[4];
            #pragma unroll
            for (int i = 0; i < 4; ++i)
                af[i] = *(const bf16x8*)&As[(wm * 64 + i * 16 + col) * 32 + quad * 8];
            #pragma unroll
            for (int j = 0; j < 4; ++j)
                bfr[j] = *(const bf16x8*)&Bs[(wn * 64 + j * 16 + col) * 32 + quad * 8];
            #pragma unroll
            for (int i = 0; i < 4; ++i)
                #pragma unroll
                for (int j = 0; j < 4; ++j)
                    acc[i][j] = __builtin_amdgcn_mfma_f32_16x16x32_bf16(af[i], bfr[j], acc[i][j], 0, 0, 0);
            __syncthreads();
        }
        qkv_epilogue_v(acc, B1, Vt, n0, m0, wm, wn, quad, col);
    } else {
        for (int k0 = 0; k0 < K_; k0 += 32) {
            #pragma unroll
            for (int h = 0; h < 2; ++h) {
                int idx = tid + h * 256;
                int row = idx >> 2, c = (idx & 3) * 8;
                G2L16(Bg + (size_t)row * K_ + k0 + c, Bs + (size_t)idx * 8);
            }
            #pragma unroll
            for (int h = 0; h < 2; ++h) {
                int idx = tid + h * 256;
                int row = idx >> 2, c = (idx & 3) * 8;
                float4 lo = *(const float4*)&Ag[(size_t)row * K_ + k0 + c];
                float4 hi = *(const float4*)&Ag[(size_t)row * K_ + k0 + c + 4];
                uint4 u;
                u.x = pk2(lo.x, lo.y); u.y = pk2(lo.z, lo.w);
                u.z = pk2(hi.x, hi.y); u.w = pk2(hi.z, hi.w);
                *(uint4*)&As[(size_t)idx * 8] = u;
            }
            __syncthreads();
            bf16x8 af[4], bfr[4];
            #pragma unroll
            for (int i = 0; i < 4; ++i)
                af[i] = *(const bf16x8*)&As[(wm * 64 + i * 16 + col) * 32 + quad * 8];
            #pragma unroll
            for (int j = 0; j < 4; ++j)
                bfr[j] = *(const bf16x8*)&Bs[(wn * 64 + j * 16 + col) * 32 + quad * 8];
            #pragma unroll
            for (int i = 0; i < 4; ++i)
                #pragma unroll
                for (int j = 0; j < 4; ++j)
                    acc[i][j] = __builtin_amdgcn_mfma_f32_16x16x32_bf16(bfr[j], af[i], acc[i][j], 0, 0, 0);
            __syncthreads();
        }
        qkv_epilogue_qk(acc, B1, Qp, Kp, which, n0, m0, wm, wn, quad, col);
    }
}

// ---------------------------------------------------------------------------
// K2: transposed-dataflow MFMA flash attention, 2 q-subtiles per wave.
// (R17's verified kernel, 102us.)
// ---------------------------------------------------------------------------
__global__ __launch_bounds__(256, 4) void attn_mfma(
    const bf16* __restrict__ Q, const bf16* __restrict__ K,
    const bf16* __restrict__ Vt, bf16* __restrict__ CTX)
{
    __shared__ bf16 Ks[64][72];         // [c][d]
    __shared__ bf16 Vs[64][72];         // [d][c]
    __shared__ bf16 Ps[4][2][16][72];   // per-wave, per-q-set P [r][c]

    const int tid  = threadIdx.x;
    const int wv   = tid >> 6;       // 0..3
    const int lane = tid & 63;
    const int col  = lane & 15;
    const int quad = lane >> 4;

    // bijective XCD swizzle: all 16 q-tiles of a bh land on one XCD
    const int lid = blockIdx.x + (blockIdx.y << 4);    // gridDim.x == 16
    const int vid = (lid & 7) * 128 + (lid >> 3);
    const int bh = vid >> 4;
    const int q0 = (vid & 15) * 128;

    const bf16* Qg  = Q  + (size_t)bh * S_ * DK_;
    const bf16* Kg  = K  + (size_t)bh * S_ * DK_;
    const bf16* Vtg = Vt + (size_t)bh * DK_ * S_;

    const short oneb = (short)0x3F80;
    const bf16x8 ones = {oneb, oneb, oneb, oneb, oneb, oneb, oneb, oneb};

    // Q fragments (B operand): lane(col) holds q-row q0 + wv*32 + qs*16 + col
    bf16x8 qf[2][2];
    #pragma unroll
    for (int qs = 0; qs < 2; ++qs) {
        const int qrow = q0 + wv * 32 + qs * 16 + col;
        qf[qs][0] = *(const bf16x8*)&Qg[(size_t)qrow * DK_ + quad * 8];
        qf[qs][1] = *(const bf16x8*)&Qg[(size_t)qrow * DK_ + 32 + quad * 8];
    }

    f32x4 o[2][4] = {};                 // O^T, d-subtiles per q-set
    f32x4 l_acc[2] = {};                // row sums, col-indexed

    const int sr = tid >> 2;            // staging row 0..63 (256 threads)
    const int e0 = (tid & 3) * 16;      // 16 bf16 (2 x b128) per thread per buf

    // prefetch tile 0
    bf16x8 kreg0 = *(const bf16x8*)&Kg[(size_t)sr * DK_ + e0];
    bf16x8 kreg1 = *(const bf16x8*)&Kg[(size_t)sr * DK_ + e0 + 8];
    bf16x8 vreg0 = *(const bf16x8*)&Vtg[(size_t)sr * S_ + e0];
    bf16x8 vreg1 = *(const bf16x8*)&Vtg[(size_t)sr * S_ + e0 + 8];

    for (int kt = 0; kt < S_ / 64; ++kt) {
        *(bf16x8*)&Ks[sr][e0]     = kreg0;
        *(bf16x8*)&Ks[sr][e0 + 8] = kreg1;
        *(bf16x8*)&Vs[sr][e0]     = vreg0;
        *(bf16x8*)&Vs[sr][e0 + 8] = vreg1;
        __syncthreads();

        if (kt + 1 < S_ / 64) {
            kreg0 = *(const bf16x8*)&Kg[(size_t)((kt + 1) * 64 + sr) * DK_ + e0];
            kreg1 = *(const bf16x8*)&Kg[(size_t)((kt + 1) * 64 + sr) * DK_ + e0 + 8];
            vreg0 = *(const bf16x8*)&Vtg[(size_t)sr * S_ + (kt + 1) * 64 + e0];
            vreg1 = *(const bf16x8*)&Vtg[(size_t)sr * S_ + (kt + 1) * 64 + e0 + 8];
        }

        // S^T = K Q^T: K-fragments loaded once, two MFMAs (one per q-set).
        #pragma unroll
        for (int cs = 0; cs < 4; ++cs) {
            const bf16* kb = &Ks[cs * 16 + col][0];
            bf16x8 ka0 = *(const bf16x8*)&kb[quad * 8];
            bf16x8 ka1 = *(const bf16x8*)&kb[32 + quad * 8];
            #pragma unroll
            for (int qs = 0; qs < 2; ++qs) {
                f32x4 a = {0.f, 0.f, 0.f, 0.f};
                a = __builtin_amdgcn_mfma_f32_16x16x32_bf16(ka0, qf[qs][0], a, 0, 0, 0);
                a = __builtin_amdgcn_mfma_f32_16x16x32_bf16(ka1, qf[qs][1], a, 0, 0, 0);
                uint2 p;
                p.x = pk2(EX2(a[0]), EX2(a[1]));
                p.y = pk2(EX2(a[2]), EX2(a[3]));
                *(uint2*)&Ps[wv][qs][col][cs * 16 + quad * 4] = p;
            }
        }

        // read P as B-frags (same wave wrote it; per-wave buffer, no barrier)
        bf16x8 pf[2][2];
        #pragma unroll
        for (int qs = 0; qs < 2; ++qs) {
            pf[qs][0] = *(const bf16x8*)&Ps[wv][qs][col][quad * 8];
            pf[qs][1] = *(const bf16x8*)&Ps[wv][qs][col][32 + quad * 8];
            // l += 1^T P (matrix pipe; every reg holds l[col])
            l_acc[qs] = __builtin_amdgcn_mfma_f32_16x16x32_bf16(ones, pf[qs][0], l_acc[qs], 0, 0, 0);
            l_acc[qs] = __builtin_amdgcn_mfma_f32_16x16x32_bf16(ones, pf[qs][1], l_acc[qs], 0, 0, 0);
        }

        // O^T += Vt P^T: V-fragments loaded once, two MFMAs each.
        #pragma unroll
        for (int ds = 0; ds < 4; ++ds) {
            const bf16* vb = &Vs[ds * 16 + col][0];
            bf16x8 va0 = *(const bf16x8*)&vb[quad * 8];
            bf16x8 va1 = *(const bf16x8*)&vb[32 + quad * 8];
            #pragma unroll
            for (int qs = 0; qs < 2; ++qs) {
                o[qs][ds] = __builtin_amdgcn_mfma_f32_16x16x32_bf16(va0, pf[qs][0], o[qs][ds], 0, 0, 0);
                o[qs][ds] = __builtin_amdgcn_mfma_f32_16x16x32_bf16(va1, pf[qs][1], o[qs][ds], 0, 0, 0);
            }
        }
        __syncthreads();
    }

    // epilogue: O^T C-layout -> 4 contiguous d per lane -> packed 8B stores
    const int b = bh >> 4, h = bh & 15;
    #pragma unroll
    for (int qs = 0; qs < 2; ++qs) {
        const float inv = 1.f / l_acc[qs][0];
        const int srow = q0 + wv * 32 + qs * 16 + col;
        bf16* crow = CTX + ((size_t)(b * S_ + srow)) * H_ + h * DK_;
        #pragma unroll
        for (int ds = 0; ds < 4; ++ds) {
            uint2 t;
            t.x = pk2(o[qs][ds][0] * inv, o[qs][ds][1] * inv);
            t.y = pk2(o[qs][ds][2] * inv, o[qs][ds][3] * inv);
            *(uint2*)&crow[ds * 16 + quad * 4] = t;
        }
    }
}

// ---------------------------------------------------------------------------
// K3: out = ctx @ W2 + b2 (MFMA), XCD-swizzled, swapped operands ->
// n-contiguous float4 epilogue (16 stores vs 64 scalar).
// ---------------------------------------------------------------------------
__global__ __launch_bounds__(256) void gemm_out_mfma(
    const bf16* __restrict__ Cx, const bf16* __restrict__ W2T,
    const float* __restrict__ B2, float* __restrict__ OUT)
{
    __shared__ bf16 As[128 * 32];
    __shared__ bf16 Bs[128 * 32];

    const int tid = threadIdx.x;
    const int lane = tid & 63, wv = tid >> 6;
    const int col = lane & 15, quad = lane >> 4;
    const int wm = wv >> 1, wn = wv & 1;
    const int lid = blockIdx.x + blockIdx.y * gridDim.x;
    const int vid = xcd_swz(lid, gridDim.x * gridDim.y);
    const int n0 = (vid % gridDim.x) * 128, m0 = (vid / gridDim.x) * 128;

    f32x4 acc[4][4] = {};

    const bf16* Ag = Cx  + (size_t)m0 * K_;
    const bf16* Bg = W2T + (size_t)n0 * K_;

    for (int k0 = 0; k0 < K_; k0 += 32) {
        #pragma unroll
        for (int h = 0; h < 2; ++h) {
            int idx = tid + h * 256;
            int row = idx >> 2, c = (idx & 3) * 8;
            G2L16(Ag + (size_t)row * K_ + k0 + c, As + (size_t)idx * 8);
            G2L16(Bg + (size_t)row * K_ + k0 + c, Bs + (size_t)idx * 8);
        }
        __syncthreads();

        bf16x8 af[4], bfr[4];
        #pragma unroll
        for (int i = 0; i < 4; ++i)
            af[i] = *(const bf16x8*)&As[(wm * 64 + i * 16 + col) * 32 + quad * 8];
        #pragma unroll
        for (int j = 0; j < 4; ++j)
            bfr[j] = *(const bf16x8*)&Bs[(wn * 64 + j * 16 + col) * 32 + quad * 8];

        #pragma unroll
        for (int i = 0; i < 4; ++i)
            #pragma unroll
            for (int j = 0; j < 4; ++j)
                acc[i][j] = __builtin_amdgcn_mfma_f32_16x16x32_bf16(bfr[j], af[i], acc[i][j], 0, 0, 0);
        __syncthreads();
    }

    // swapped C-layout: m = col-side, n = reg-side (4 consecutive n per lane)
    #pragma unroll
    for (int i = 0; i < 4; ++i) {
        int m = m0 + wm * 64 + i * 16 + col;
        #pragma unroll
        for (int j = 0; j < 4; ++j) {
            int n = n0 + wn * 64 + j * 16 + quad * 4;
            float4 b = *(const float4*)&B2[n];
            float4 t;
            t.x = acc[i][j][0] + b.x;
            t.y = acc[i][j][1] + b.y;
            t.z = acc[i][j][2] + b.z;
            t.w = acc[i][j][3] + b.w;
            *(float4*)&OUT[(size_t)m * H_ + n] = t;
        }
    }
}

// ---------------------------------------------------------------------------
extern "C" void kernel_launch(void* const* d_in, const int* in_sizes, int n_in,
                              void* d_out, int out_size, void* d_ws, size_t ws_size,
                              hipStream_t stream)
{
    const float* X  = (const float*)d_in[0];
    const float* W1 = (const float*)d_in[1];
    const float* B1 = (const float*)d_in[2];
    const float* W2 = (const float*)d_in[3];
    const float* B2 = (const float*)d_in[4];
    float* OUT = (float*)d_out;

    const size_t QE = (size_t)B_ * NH_ * S_ * DK_;   // 8,388,608
    bf16* Qw  = (bf16*)d_ws;
    bf16* Kw  = Qw + QE;
    bf16* Vw  = Kw + QE;        // transposed [bh][d][s]
    bf16* Rw  = Vw + QE;        // W1T during qkv, ctx afterwards
    bf16* W1T = Rw;
    bf16* Cw  = Rw;
    bf16* W2T = Qw;             // overlays Q (dead after attn)
    bf16* Xb  = Rw + QE;        // only if ws permits (5*QE elems total)

    const bool fast = ws_size >= 5 * QE * sizeof(bf16);

    conv_wT<<<dim3(N1_ / 64, K_ / 64), 256, 0, stream>>>(W1, W1T, K_, N1_);
    if (fast) {
        conv_x<<<dim3((int)(QE / (256 * 8))), 256, 0, stream>>>(X, Xb);
        gemm_qkv_mfma2<<<dim3(N1_ / 128, M_ / 128), 256, 0, stream>>>(Xb, W1T, B1, Qw, Kw, Vw);
    } else {
        gemm_qkv_mfma<<<dim3(N1_ / 128, M_ / 128), 256, 0, stream>>>(X, W1T, B1, Qw, Kw, Vw);
    }
    attn_mfma<<<dim3(S_ / 128, B_ * NH_), 256, 0, stream>>>(Qw, Kw, Vw, Cw);
    conv_wT<<<dim3(H_ / 64, K_ / 64), 256, 0, stream>>>(W2, W2T, K_, H_);
    gemm_out_mfma<<<dim3(H_ / 128, M_ / 128), 256, 0, stream>>>(Cw, W2T, B2, OUT);
}

// Round 13
// 290.149 us; speedup vs baseline: 1.1476x; 1.0173x over previous
//
#include <hip/hip_runtime.h>
#include <hip/hip_bf16.h>

// Problem: B=4, S=2048, H=1024, NH=16, DK=64. fp32 I/O.
// R21: consolidation to R17's proven-best GEMM/attn state (operand-swap
// experiment R19/R20 inconclusive-negative within ~2.5% run noise; reverted)
// + ONE new change: the three converter kernels (conv_x, conv_wT(W1),
// conv_wT(W2)) fuse into a single launch with disjoint blockIdx ranges,
// cutting the serialized kernel count 6 -> 4 (launch-gap recovery). W2T is
// placed past the 5*QE workspace mark when ws permits (guarded; exact R17
// sequence otherwise). All compute kernels byte-identical to R17.

typedef __hip_bfloat16 bf16;
typedef __attribute__((ext_vector_type(8))) short bf16x8;  // 8 bf16 = 4 VGPRs
typedef __attribute__((ext_vector_type(4))) float f32x4;

#define B_   4
#define S_   2048
#define H_   1024
#define NH_  16
#define DK_  64
#define M_   8192   // B_*S_
#define N1_  3072
#define K_   1024

#define SCALE_Q 0.18033688f   // 0.125 * log2(e): softmax in exp2 domain

typedef const __attribute__((address_space(1))) void* gas_t;
typedef __attribute__((address_space(3))) void* las_t;
#define G2L16(g, l) __builtin_amdgcn_global_load_lds((gas_t)(g), (las_t)(l), 16, 0, 0)

#if __has_builtin(__builtin_amdgcn_exp2f)
#define EX2(x) __builtin_amdgcn_exp2f(x)
#else
#define EX2(x) exp2f(x)
#endif

__device__ __forceinline__ float b2f(bf16 v) { return __bfloat162float(v); }

// pack two fp32 -> two bf16 (RNE, finite inputs), 3 int ops + merge
__device__ __forceinline__ unsigned pk2(float a, float b) {
    unsigned ua = __float_as_uint(a);
    unsigned ub = __float_as_uint(b);
    ua += 0x7FFFu + ((ua >> 16) & 1u);
    ub += 0x7FFFu + ((ub >> 16) & 1u);
    return (ua >> 16) | (ub & 0xFFFF0000u);
}

// bijective XCD swizzle for linear block id (nwg % 8 == 0)
__device__ __forceinline__ int xcd_swz(int lid, int nwg) {
    return (lid & 7) * (nwg >> 3) + (lid >> 3);
}

// ---------------------------------------------------------------------------
// Fused converters: one launch.
//  blocks [0, 4096):        X fp32 -> bf16 (conv_x)
//  blocks [4096, 4864):     W1 [K][N1] -> W1T [N1][K] bf16   (768 blocks)
//  blocks [4864, 5120):     W2 [K][H]  -> W2T [H][K] bf16    (256 blocks)
// Grid may stop at 4864 when W2T has no early home (ws too small).
// ---------------------------------------------------------------------------
__global__ __launch_bounds__(256) void conv_fused(
    const float* __restrict__ X,  bf16* __restrict__ Xb,
    const float* __restrict__ W1, bf16* __restrict__ W1T,
    const float* __restrict__ W2, bf16* __restrict__ W2T)
{
    const int bid = blockIdx.x;
    const int tid = threadIdx.x;
    __shared__ bf16 T[64][72];

    if (bid < 4096) {
        size_t i = ((size_t)bid * 256 + tid) * 8;
        float4 lo = *(const float4*)&X[i];
        float4 hi = *(const float4*)&X[i + 4];
        uint4 u;
        u.x = pk2(lo.x, lo.y); u.y = pk2(lo.z, lo.w);
        u.z = pk2(hi.x, hi.y); u.w = pk2(hi.z, hi.w);
        *(uint4*)&Xb[i] = u;
        return;
    }

    const float* W; bf16* WT; int Ndim; int t;
    if (bid < 4096 + 768) { t = bid - 4096; W = W1; WT = W1T; Ndim = N1_; }
    else                  { t = bid - 4864; W = W2; WT = W2T; Ndim = H_;  }
    const int nx = Ndim >> 6;
    const int n0 = (t % nx) * 64, k0 = (t / nx) * 64;
    const int kr = tid >> 4, nc = (tid & 15) * 4;
    #pragma unroll
    for (int p = 0; p < 4; ++p) {
        float4 v = *(const float4*)&W[(size_t)(k0 + kr + p * 16) * Ndim + n0 + nc];
        T[nc + 0][kr + p * 16] = __float2bfloat16(v.x);
        T[nc + 1][kr + p * 16] = __float2bfloat16(v.y);
        T[nc + 2][kr + p * 16] = __float2bfloat16(v.z);
        T[nc + 3][kr + p * 16] = __float2bfloat16(v.w);
    }
    __syncthreads();
    const int nr = tid >> 2, kc = (tid & 3) * 16;
    *(bf16x8*)&WT[(size_t)(n0 + nr) * K_ + k0 + kc]     = *(const bf16x8*)&T[nr][kc];
    *(bf16x8*)&WT[(size_t)(n0 + nr) * K_ + k0 + kc + 8] = *(const bf16x8*)&T[nr][kc + 8];
}

// ---------------------------------------------------------------------------
// K0: standalone convert + transpose (fallback path / late W2T).
// ---------------------------------------------------------------------------
__global__ __launch_bounds__(256) void conv_wT(const float* __restrict__ W,
                                               bf16* __restrict__ WT,
                                               int Kdim, int Ndim)
{
    __shared__ bf16 T[64][72];
    const int tid = threadIdx.x;
    const int n0 = blockIdx.x * 64, k0 = blockIdx.y * 64;
    const int kr = tid >> 4, nc = (tid & 15) * 4;
    #pragma unroll
    for (int p = 0; p < 4; ++p) {
        float4 v = *(const float4*)&W[(size_t)(k0 + kr + p * 16) * Ndim + n0 + nc];
        T[nc + 0][kr + p * 16] = __float2bfloat16(v.x);
        T[nc + 1][kr + p * 16] = __float2bfloat16(v.y);
        T[nc + 2][kr + p * 16] = __float2bfloat16(v.z);
        T[nc + 3][kr + p * 16] = __float2bfloat16(v.w);
    }
    __syncthreads();
    const int nr = tid >> 2, kc = (tid & 3) * 16;
    *(bf16x8*)&WT[(size_t)(n0 + nr) * Kdim + k0 + kc]     = *(const bf16x8*)&T[nr][kc];
    *(bf16x8*)&WT[(size_t)(n0 + nr) * Kdim + k0 + kc + 8] = *(const bf16x8*)&T[nr][kc + 8];
}

// ---------------------------------------------------------------------------
// qkv epilogue shared by both variants (R17)
// ---------------------------------------------------------------------------
__device__ __forceinline__ void qkv_epilogue(
    const f32x4 acc[4][4], const float* __restrict__ B1,
    bf16* __restrict__ Qp, bf16* __restrict__ Kp, bf16* __restrict__ Vt,
    int n0, int m0, int wm, int wn, int quad, int col)
{
    const int which = n0 >> 10;          // 0=q 1=k 2=v
    const int bb = m0 >> 11;
    if (which == 2) {
        #pragma unroll
        for (int i = 0; i < 4; ++i) {
            int s = (m0 & (S_ - 1)) + wm * 64 + i * 16 + quad * 4;
            #pragma unroll
            for (int j = 0; j < 4; ++j) {
                int n = n0 + wn * 64 + j * 16 + col;
                int h = (n >> 6) & 15, d = n & 63;
                float bv = B1[n];
                uint2 t;
                t.x = pk2(acc[i][j][0] + bv, acc[i][j][1] + bv);
                t.y = pk2(acc[i][j][2] + bv, acc[i][j][3] + bv);
                *(uint2*)&Vt[(((size_t)(bb * NH_ + h)) * DK_ + d) * S_ + s] = t;
            }
        }
    } else {
        bf16* dst = which ? Kp : Qp;
        const float sc = which ? 1.0f : SCALE_Q;
        #pragma unroll
        for (int i = 0; i < 4; ++i) {
            #pragma unroll
            for (int r = 0; r < 4; ++r) {
                int s = (m0 & (S_ - 1)) + wm * 64 + i * 16 + quad * 4 + r;
                #pragma unroll
                for (int j = 0; j < 4; ++j) {
                    int n = n0 + wn * 64 + j * 16 + col;
                    int h = (n >> 6) & 15, d = n & 63;
                    dst[(((size_t)(bb * NH_ + h)) * S_ + s) * DK_ + d] =
                        __float2bfloat16((acc[i][j][r] + B1[n]) * sc);
                }
            }
        }
    }
}

// ---------------------------------------------------------------------------
// K1-fast: qkv = Xbf @ W1 + b1, pure m97 (G2L16 both operands), XCD-swizzled.
// (R17 verbatim.)
// ---------------------------------------------------------------------------
__global__ __launch_bounds__(256) void gemm_qkv_mfma2(
    const bf16* __restrict__ Xb, const bf16* __restrict__ W1T,
    const float* __restrict__ B1,
    bf16* __restrict__ Qp, bf16* __restrict__ Kp, bf16* __restrict__ Vt)
{
    __shared__ bf16 As[128 * 32];
    __shared__ bf16 Bs[128 * 32];

    const int tid = threadIdx.x;
    const int lane = tid & 63, wv = tid >> 6;
    const int col = lane & 15, quad = lane >> 4;
    const int wm = wv >> 1, wn = wv & 1;
    const int lid = blockIdx.x + blockIdx.y * gridDim.x;
    const int vid = xcd_swz(lid, gridDim.x * gridDim.y);
    const int n0 = (vid % gridDim.x) * 128, m0 = (vid / gridDim.x) * 128;

    f32x4 acc[4][4] = {};

    const bf16* Ag = Xb  + (size_t)m0 * K_;
    const bf16* Bg = W1T + (size_t)n0 * K_;

    for (int k0 = 0; k0 < K_; k0 += 32) {
        #pragma unroll
        for (int h = 0; h < 2; ++h) {
            int idx = tid + h * 256;
            int row = idx >> 2, c = (idx & 3) * 8;
            G2L16(Ag + (size_t)row * K_ + k0 + c, As + (size_t)idx * 8);
            G2L16(Bg + (size_t)row * K_ + k0 + c, Bs + (size_t)idx * 8);
        }
        __syncthreads();

        bf16x8 af[4], bfr[4];
        #pragma unroll
        for (int i = 0; i < 4; ++i)
            af[i] = *(const bf16x8*)&As[(wm * 64 + i * 16 + col) * 32 + quad * 8];
        #pragma unroll
        for (int j = 0; j < 4; ++j)
            bfr[j] = *(const bf16x8*)&Bs[(wn * 64 + j * 16 + col) * 32 + quad * 8];

        #pragma unroll
        for (int i = 0; i < 4; ++i)
            #pragma unroll
            for (int j = 0; j < 4; ++j)
                acc[i][j] = __builtin_amdgcn_mfma_f32_16x16x32_bf16(af[i], bfr[j], acc[i][j], 0, 0, 0);
        __syncthreads();
    }
    qkv_epilogue(acc, B1, Qp, Kp, Vt, n0, m0, wm, wn, quad, col);
}

// ---------------------------------------------------------------------------
// K1-fallback: qkv with in-loop fp32->bf16 A conversion, XCD-swizzled.
// (R17 verbatim.)
// ---------------------------------------------------------------------------
__global__ __launch_bounds__(256) void gemm_qkv_mfma(
    const float* __restrict__ X, const bf16* __restrict__ W1T,
    const float* __restrict__ B1,
    bf16* __restrict__ Qp, bf16* __restrict__ Kp, bf16* __restrict__ Vt)
{
    __shared__ bf16 As[128 * 32];
    __shared__ bf16 Bs[128 * 32];

    const int tid = threadIdx.x;
    const int lane = tid & 63, wv = tid >> 6;
    const int col = lane & 15, quad = lane >> 4;
    const int wm = wv >> 1, wn = wv & 1;
    const int lid = blockIdx.x + blockIdx.y * gridDim.x;
    const int vid = xcd_swz(lid, gridDim.x * gridDim.y);
    const int n0 = (vid % gridDim.x) * 128, m0 = (vid / gridDim.x) * 128;

    f32x4 acc[4][4] = {};

    const float* Ag = X   + (size_t)m0 * K_;
    const bf16*  Bg = W1T + (size_t)n0 * K_;

    for (int k0 = 0; k0 < K_; k0 += 32) {
        #pragma unroll
        for (int h = 0; h < 2; ++h) {
            int idx = tid + h * 256;
            int row = idx >> 2, c = (idx & 3) * 8;
            G2L16(Bg + (size_t)row * K_ + k0 + c, Bs + (size_t)idx * 8);
        }
        #pragma unroll
        for (int h = 0; h < 2; ++h) {
            int idx = tid + h * 256;
            int row = idx >> 2, c = (idx & 3) * 8;
            float4 lo = *(const float4*)&Ag[(size_t)row * K_ + k0 + c];
            float4 hi = *(const float4*)&Ag[(size_t)row * K_ + k0 + c + 4];
            uint4 u;
            u.x = pk2(lo.x, lo.y); u.y = pk2(lo.z, lo.w);
            u.z = pk2(hi.x, hi.y); u.w = pk2(hi.z, hi.w);
            *(uint4*)&As[(size_t)idx * 8] = u;
        }
        __syncthreads();

        bf16x8 af[4], bfr[4];
        #pragma unroll
        for (int i = 0; i < 4; ++i)
            af[i] = *(const bf16x8*)&As[(wm * 64 + i * 16 + col) * 32 + quad * 8];
        #pragma unroll
        for (int j = 0; j < 4; ++j)
            bfr[j] = *(const bf16x8*)&Bs[(wn * 64 + j * 16 + col) * 32 + quad * 8];

        #pragma unroll
        for (int i = 0; i < 4; ++i)
            #pragma unroll
            for (int j = 0; j < 4; ++j)
                acc[i][j] = __builtin_amdgcn_mfma_f32_16x16x32_bf16(af[i], bfr[j], acc[i][j], 0, 0, 0);
        __syncthreads();
    }
    qkv_epilogue(acc, B1, Qp, Kp, Vt, n0, m0, wm, wn, quad, col);
}

// ---------------------------------------------------------------------------
// K2: transposed-dataflow MFMA flash attention, 2 q-subtiles per wave.
// (R17's verified 102us kernel, verbatim.)
// ---------------------------------------------------------------------------
__global__ __launch_bounds__(256, 4) void attn_mfma(
    const bf16* __restrict__ Q, const bf16* __restrict__ K,
    const bf16* __restrict__ Vt, bf16* __restrict__ CTX)
{
    __shared__ bf16 Ks[64][72];         // [c][d]
    __shared__ bf16 Vs[64][72];         // [d][c]
    __shared__ bf16 Ps[4][2][16][72];   // per-wave, per-q-set P [r][c]

    const int tid  = threadIdx.x;
    const int wv   = tid >> 6;       // 0..3
    const int lane = tid & 63;
    const int col  = lane & 15;
    const int quad = lane >> 4;

    // bijective XCD swizzle: all 16 q-tiles of a bh land on one XCD
    const int lid = blockIdx.x + (blockIdx.y << 4);    // gridDim.x == 16
    const int vid = (lid & 7) * 128 + (lid >> 3);
    const int bh = vid >> 4;
    const int q0 = (vid & 15) * 128;

    const bf16* Qg  = Q  + (size_t)bh * S_ * DK_;
    const bf16* Kg  = K  + (size_t)bh * S_ * DK_;
    const bf16* Vtg = Vt + (size_t)bh * DK_ * S_;

    const short oneb = (short)0x3F80;
    const bf16x8 ones = {oneb, oneb, oneb, oneb, oneb, oneb, oneb, oneb};

    // Q fragments (B operand): lane(col) holds q-row q0 + wv*32 + qs*16 + col
    bf16x8 qf[2][2];
    #pragma unroll
    for (int qs = 0; qs < 2; ++qs) {
        const int qrow = q0 + wv * 32 + qs * 16 + col;
        qf[qs][0] = *(const bf16x8*)&Qg[(size_t)qrow * DK_ + quad * 8];
        qf[qs][1] = *(const bf16x8*)&Qg[(size_t)qrow * DK_ + 32 + quad * 8];
    }

    f32x4 o[2][4] = {};                 // O^T, d-subtiles per q-set
    f32x4 l_acc[2] = {};                // row sums, col-indexed

    const int sr = tid >> 2;            // staging row 0..63 (256 threads)
    const int e0 = (tid & 3) * 16;      // 16 bf16 (2 x b128) per thread per buf

    // prefetch tile 0
    bf16x8 kreg0 = *(const bf16x8*)&Kg[(size_t)sr * DK_ + e0];
    bf16x8 kreg1 = *(const bf16x8*)&Kg[(size_t)sr * DK_ + e0 + 8];
    bf16x8 vreg0 = *(const bf16x8*)&Vtg[(size_t)sr * S_ + e0];
    bf16x8 vreg1 = *(const bf16x8*)&Vtg[(size_t)sr * S_ + e0 + 8];

    for (int kt = 0; kt < S_ / 64; ++kt) {
        *(bf16x8*)&Ks[sr][e0]     = kreg0;
        *(bf16x8*)&Ks[sr][e0 + 8] = kreg1;
        *(bf16x8*)&Vs[sr][e0]     = vreg0;
        *(bf16x8*)&Vs[sr][e0 + 8] = vreg1;
        __syncthreads();

        if (kt + 1 < S_ / 64) {
            kreg0 = *(const bf16x8*)&Kg[(size_t)((kt + 1) * 64 + sr) * DK_ + e0];
            kreg1 = *(const bf16x8*)&Kg[(size_t)((kt + 1) * 64 + sr) * DK_ + e0 + 8];
            vreg0 = *(const bf16x8*)&Vtg[(size_t)sr * S_ + (kt + 1) * 64 + e0];
            vreg1 = *(const bf16x8*)&Vtg[(size_t)sr * S_ + (kt + 1) * 64 + e0 + 8];
        }

        // S^T = K Q^T: K-fragments loaded once, two MFMAs (one per q-set).
        #pragma unroll
        for (int cs = 0; cs < 4; ++cs) {
            const bf16* kb = &Ks[cs * 16 + col][0];
            bf16x8 ka0 = *(const bf16x8*)&kb[quad * 8];
            bf16x8 ka1 = *(const bf16x8*)&kb[32 + quad * 8];
            #pragma unroll
            for (int qs = 0; qs < 2; ++qs) {
                f32x4 a = {0.f, 0.f, 0.f, 0.f};
                a = __builtin_amdgcn_mfma_f32_16x16x32_bf16(ka0, qf[qs][0], a, 0, 0, 0);
                a = __builtin_amdgcn_mfma_f32_16x16x32_bf16(ka1, qf[qs][1], a, 0, 0, 0);
                uint2 p;
                p.x = pk2(EX2(a[0]), EX2(a[1]));
                p.y = pk2(EX2(a[2]), EX2(a[3]));
                *(uint2*)&Ps[wv][qs][col][cs * 16 + quad * 4] = p;
            }
        }

        // read P as B-frags (same wave wrote it; per-wave buffer, no barrier)
        bf16x8 pf[2][2];
        #pragma unroll
        for (int qs = 0; qs < 2; ++qs) {
            pf[qs][0] = *(const bf16x8*)&Ps[wv][qs][col][quad * 8];
            pf[qs][1] = *(const bf16x8*)&Ps[wv][qs][col][32 + quad * 8];
            // l += 1^T P (matrix pipe; every reg holds l[col])
            l_acc[qs] = __builtin_amdgcn_mfma_f32_16x16x32_bf16(ones, pf[qs][0], l_acc[qs], 0, 0, 0);
            l_acc[qs] = __builtin_amdgcn_mfma_f32_16x16x32_bf16(ones, pf[qs][1], l_acc[qs], 0, 0, 0);
        }

        // O^T += Vt P^T: V-fragments loaded once, two MFMAs each.
        #pragma unroll
        for (int ds = 0; ds < 4; ++ds) {
            const bf16* vb = &Vs[ds * 16 + col][0];
            bf16x8 va0 = *(const bf16x8*)&vb[quad * 8];
            bf16x8 va1 = *(const bf16x8*)&vb[32 + quad * 8];
            #pragma unroll
            for (int qs = 0; qs < 2; ++qs) {
                o[qs][ds] = __builtin_amdgcn_mfma_f32_16x16x32_bf16(va0, pf[qs][0], o[qs][ds], 0, 0, 0);
                o[qs][ds] = __builtin_amdgcn_mfma_f32_16x16x32_bf16(va1, pf[qs][1], o[qs][ds], 0, 0, 0);
            }
        }
        __syncthreads();
    }

    // epilogue: O^T C-layout -> 4 contiguous d per lane -> packed 8B stores
    const int b = bh >> 4, h = bh & 15;
    #pragma unroll
    for (int qs = 0; qs < 2; ++qs) {
        const float inv = 1.f / l_acc[qs][0];
        const int srow = q0 + wv * 32 + qs * 16 + col;
        bf16* crow = CTX + ((size_t)(b * S_ + srow)) * H_ + h * DK_;
        #pragma unroll
        for (int ds = 0; ds < 4; ++ds) {
            uint2 t;
            t.x = pk2(o[qs][ds][0] * inv, o[qs][ds][1] * inv);
            t.y = pk2(o[qs][ds][2] * inv, o[qs][ds][3] * inv);
            *(uint2*)&crow[ds * 16 + quad * 4] = t;
        }
    }
}

// ---------------------------------------------------------------------------
// K3: out = ctx @ W2 + b2 (MFMA), XCD-swizzled. (R17 verbatim.)
// ---------------------------------------------------------------------------
__global__ __launch_bounds__(256) void gemm_out_mfma(
    const bf16* __restrict__ Cx, const bf16* __restrict__ W2T,
    const float* __restrict__ B2, float* __restrict__ OUT)
{
    __shared__ bf16 As[128 * 32];
    __shared__ bf16 Bs[128 * 32];

    const int tid = threadIdx.x;
    const int lane = tid & 63, wv = tid >> 6;
    const int col = lane & 15, quad = lane >> 4;
    const int wm = wv >> 1, wn = wv & 1;
    const int lid = blockIdx.x + blockIdx.y * gridDim.x;
    const int vid = xcd_swz(lid, gridDim.x * gridDim.y);
    const int n0 = (vid % gridDim.x) * 128, m0 = (vid / gridDim.x) * 128;

    f32x4 acc[4][4] = {};

    const bf16* Ag = Cx  + (size_t)m0 * K_;
    const bf16* Bg = W2T + (size_t)n0 * K_;

    for (int k0 = 0; k0 < K_; k0 += 32) {
        #pragma unroll
        for (int h = 0; h < 2; ++h) {
            int idx = tid + h * 256;
            int row = idx >> 2, c = (idx & 3) * 8;
            G2L16(Ag + (size_t)row * K_ + k0 + c, As + (size_t)idx * 8);
            G2L16(Bg + (size_t)row * K_ + k0 + c, Bs + (size_t)idx * 8);
        }
        __syncthreads();

        bf16x8 af[4], bfr[4];
        #pragma unroll
        for (int i = 0; i < 4; ++i)
            af[i] = *(const bf16x8*)&As[(wm * 64 + i * 16 + col) * 32 + quad * 8];
        #pragma unroll
        for (int j = 0; j < 4; ++j)
            bfr[j] = *(const bf16x8*)&Bs[(wn * 64 + j * 16 + col) * 32 + quad * 8];

        #pragma unroll
        for (int i = 0; i < 4; ++i)
            #pragma unroll
            for (int j = 0; j < 4; ++j)
                acc[i][j] = __builtin_amdgcn_mfma_f32_16x16x32_bf16(af[i], bfr[j], acc[i][j], 0, 0, 0);
        __syncthreads();
    }

    #pragma unroll
    for (int i = 0; i < 4; ++i) {
        #pragma unroll
        for (int r = 0; r < 4; ++r) {
            int m = m0 + wm * 64 + i * 16 + quad * 4 + r;
            #pragma unroll
            for (int j = 0; j < 4; ++j) {
                int n = n0 + wn * 64 + j * 16 + col;
                OUT[(size_t)m * H_ + n] = acc[i][j][r] + B2[n];
            }
        }
    }
}

// ---------------------------------------------------------------------------
extern "C" void kernel_launch(void* const* d_in, const int* in_sizes, int n_in,
                              void* d_out, int out_size, void* d_ws, size_t ws_size,
                              hipStream_t stream)
{
    const float* X  = (const float*)d_in[0];
    const float* W1 = (const float*)d_in[1];
    const float* B1 = (const float*)d_in[2];
    const float* W2 = (const float*)d_in[3];
    const float* B2 = (const float*)d_in[4];
    float* OUT = (float*)d_out;

    const size_t QE = (size_t)B_ * NH_ * S_ * DK_;   // 8,388,608
    const size_t WE = (size_t)H_ * K_;               // 1,048,576 (W2T elems)
    bf16* Qw  = (bf16*)d_ws;
    bf16* Kw  = Qw + QE;
    bf16* Vw  = Kw + QE;        // transposed [bh][d][s]
    bf16* Rw  = Vw + QE;        // W1T during qkv, ctx afterwards
    bf16* W1T = Rw;
    bf16* Cw  = Rw;
    bf16* Xb  = Rw + QE;        // fast path only (5*QE elems total)
    bf16* W2Te = Xb + QE;       // early W2T home (needs 5*QE + WE elems)

    const bool fast    = ws_size >= 5 * QE * sizeof(bf16);
    const bool earlyW2 = ws_size >= (5 * QE + WE) * sizeof(bf16);

    if (fast) {
        // one fused converter launch: conv_x + W1T (+ W2T when it has a home)
        conv_fused<<<dim3(earlyW2 ? 5120 : 4864), 256, 0, stream>>>(
            X, Xb, W1, W1T, W2, W2Te);
        gemm_qkv_mfma2<<<dim3(N1_ / 128, M_ / 128), 256, 0, stream>>>(Xb, W1T, B1, Qw, Kw, Vw);
        attn_mfma<<<dim3(S_ / 128, B_ * NH_), 256, 0, stream>>>(Qw, Kw, Vw, Cw);
        bf16* W2T = earlyW2 ? W2Te : Qw;    // Qw dead after attn
        if (!earlyW2)
            conv_wT<<<dim3(H_ / 64, K_ / 64), 256, 0, stream>>>(W2, W2T, K_, H_);
        gemm_out_mfma<<<dim3(H_ / 128, M_ / 128), 256, 0, stream>>>(Cw, W2T, B2, OUT);
    } else {
        bf16* W2T = Qw;
        conv_wT<<<dim3(N1_ / 64, K_ / 64), 256, 0, stream>>>(W1, W1T, K_, N1_);
        gemm_qkv_mfma<<<dim3(N1_ / 128, M_ / 128), 256, 0, stream>>>(X, W1T, B1, Qw, Kw, Vw);
        attn_mfma<<<dim3(S_ / 128, B_ * NH_), 256, 0, stream>>>(Qw, Kw, Vw, Cw);
        conv_wT<<<dim3(H_ / 64, K_ / 64), 256, 0, stream>>>(W2, W2T, K_, H_);
        gemm_out_mfma<<<dim3(H_ / 128, M_ / 128), 256, 0, stream>>>(Cw, W2T, B2, OUT);
    }
}